// Round 9
// baseline (211.417 us; speedup 1.0000x reference)
//
#include <hip/hip_runtime.h>

typedef __bf16 bf16_t;
typedef __bf16 bf16x8 __attribute__((ext_vector_type(8)));
typedef __bf16 bf16x4 __attribute__((ext_vector_type(4)));
typedef float f32x4 __attribute__((ext_vector_type(4)));

#define D_MODEL 1024
#define NHEAD 16
#define HD 64
#define XLEN 1024
#define TLEN 4096
#define NBATCH 2
#define CEXP 0.18033688011112042f /* log2(e)/sqrt(64) */

typedef __attribute__((address_space(3))) bf16_t lds_bf16;
typedef const __attribute__((address_space(1))) bf16_t glb_bf16;

#define MEMFENCE() asm volatile("" ::: "memory")

// ---------------- convert: fp32 -> bf16, 5 arrays in one launch ----------------
__global__ __launch_bounds__(256) void convert5(const float* __restrict__ prev, const float* __restrict__ ctx,
                                                const float* __restrict__ wq, const float* __restrict__ wk,
                                                const float* __restrict__ wv,
                                                bf16_t* __restrict__ prev_b, bf16_t* __restrict__ ctx_b,
                                                bf16_t* __restrict__ wq_b, bf16_t* __restrict__ wk_b,
                                                bf16_t* __restrict__ wv_b) {
    int b = blockIdx.x;
    const float* src; bf16_t* dst; int lb;
    if (b < 256)       { src = prev; dst = prev_b; lb = b; }
    else if (b < 1280) { src = ctx;  dst = ctx_b;  lb = b - 256; }
    else if (b < 1408) { src = wq;   dst = wq_b;   lb = b - 1280; }
    else if (b < 1536) { src = wk;   dst = wk_b;   lb = b - 1408; }
    else               { src = wv;   dst = wv_b;   lb = b - 1536; }
    const int base = lb * 8192 + threadIdx.x * 4;
#pragma unroll
    for (int i = 0; i < 8; ++i) {
        const int off = base + i * 1024;
        f32x4 f = *(const f32x4*)(src + off);
        bf16x4 h;
        h[0] = (bf16_t)f[0]; h[1] = (bf16_t)f[1]; h[2] = (bf16_t)f[2]; h[3] = (bf16_t)f[3];
        *(bf16x4*)(dst + off) = h;
    }
}

// ---------------- projection GEMM core: BK=32, ring-2 LDS (R4-verified), MF=4 ----------------
// Subtile = 16x32 bf16 (1024B), st_16x32 swizzle on both the pre-swizzled global source
// (linear global_load_lds dest) and the ds_read_b128 fragment address.
// Per buffer: A = 8 subtiles (8KB), B = 16 subtiles (16KB) -> BUFSZ 24KB, ring-2 = 48KB LDS.
// launch_bounds(512,4) -> reg cap 128/lane; MF=4 needs ~124 (60 VGPR + 64 acc) -> fits,
// giving 2 blocks/CU residency (R7 measured 1 block/CU at (512,2): Occupancy 25%).
template<int MF>   // MF = 4: BM=128, BN=256
__device__ __forceinline__ void gemm_core(const bf16_t* __restrict__ Xa,
                                          const bf16_t* __restrict__ Wb,
                                          int m0, int n0, char* smem,
                                          f32x4 (&acc)[MF][4]) {
    const int tid  = threadIdx.x;
    const int w    = tid >> 6;
    const int lane = tid & 63;
    const int q4   = lane >> 4;
    const int c    = lane & 15;
    const int wm   = w >> 2;     // 0..1 : M half
    const int wn   = w & 3;      // 0..3 : 64-col group

    constexpr int ABYTES = MF * 2048;        // A bytes per buffer (8KB at MF=4)
    constexpr int BUFSZ  = ABYTES + 16384;   // + B 16KB
    constexpr int AINSTR = MF / 4;           // global_load_lds instrs for A per tile
    constexpr int NT     = 32;               // K / BK = 1024/32

#pragma unroll
    for (int i = 0; i < MF; ++i)
#pragma unroll
        for (int j = 0; j < 4; ++j) acc[i][j] = (f32x4){0.f, 0.f, 0.f, 0.f};

    // staging source (per-lane, pre-swizzled): lane covers subtile row lane>>2, chunk lane&3
    const int xp = ((lane & 3) * 16) ^ (((lane >> 5) & 1) << 5);
    const char* gA = (const char*)Xa + ((size_t)(m0 + w * 16 + (lane >> 2)) << 11) + xp;
    const char* gB = (const char*)Wb + ((size_t)(n0 + w * 16 + (lane >> 2)) << 11) + xp;
    char* lw = smem + w * 1024;              // wave fills subtile (group*8 + w)

    // fragment read offset (within subtile): row c, col-chunk q4, swizzled
    const int fo = c * 64 + ((q4 * 16) ^ (((c >> 3) & 1) << 5));

    // prologue: stage tile 0 into buffer 0
#pragma unroll
    for (int i = 0; i < AINSTR; ++i)
        __builtin_amdgcn_global_load_lds((glb_bf16*)(gA + (size_t)i * 262144),
                                         (lds_bf16*)(lw + i * 8192), 16, 0, 0);
#pragma unroll
    for (int i = 0; i < 2; ++i)
        __builtin_amdgcn_global_load_lds((glb_bf16*)(gB + (size_t)i * 262144),
                                         (lds_bf16*)(lw + ABYTES + i * 8192), 16, 0, 0);
    MEMFENCE();

#pragma unroll 1
    for (int t = 0; t < NT; ++t) {
        // tile t's loads are the only outstanding VMEM ops
        asm volatile("s_waitcnt vmcnt(0)" ::: "memory");
        __builtin_amdgcn_s_barrier();
        MEMFENCE();

        // prefetch t+1 into the other buffer (sealed: its readers passed the barrier)
        if (t + 1 < NT) {
            char* pbuf = lw + ((t + 1) & 1) * BUFSZ;
            const int tk = (t + 1) * 64;
#pragma unroll
            for (int i = 0; i < AINSTR; ++i)
                __builtin_amdgcn_global_load_lds((glb_bf16*)(gA + (size_t)i * 262144 + tk),
                                                 (lds_bf16*)(pbuf + i * 8192), 16, 0, 0);
#pragma unroll
            for (int i = 0; i < 2; ++i)
                __builtin_amdgcn_global_load_lds((glb_bf16*)(gB + (size_t)i * 262144 + tk),
                                                 (lds_bf16*)(pbuf + ABYTES + i * 8192), 16, 0, 0);
        }

        const char* cbuf = smem + (t & 1) * BUFSZ;

        bf16x8 bfrag[4];
#pragma unroll
        for (int ni = 0; ni < 4; ++ni)
            bfrag[ni] = *(const bf16x8*)(cbuf + ABYTES + (wn * 4 + ni) * 1024 + fo);
        bf16x8 afrag[MF / 2];
#pragma unroll
        for (int mi = 0; mi < MF / 2; ++mi)
            afrag[mi] = *(const bf16x8*)(cbuf + (wm * MF + mi) * 1024 + fo);
        __builtin_amdgcn_s_setprio(1);
#pragma unroll
        for (int mi = 0; mi < MF / 2; ++mi)
#pragma unroll
            for (int ni = 0; ni < 4; ++ni)
                acc[mi][ni] = __builtin_amdgcn_mfma_f32_16x16x32_bf16(afrag[mi], bfrag[ni], acc[mi][ni], 0, 0, 0);
        __builtin_amdgcn_s_setprio(0);

        bf16x8 afrag2[MF / 2];
#pragma unroll
        for (int mi = 0; mi < MF / 2; ++mi)
            afrag2[mi] = *(const bf16x8*)(cbuf + (wm * MF + MF / 2 + mi) * 1024 + fo);
        __builtin_amdgcn_s_setprio(1);
#pragma unroll
        for (int mi = 0; mi < MF / 2; ++mi)
#pragma unroll
            for (int ni = 0; ni < 4; ++ni)
                acc[MF / 2 + mi][ni] = __builtin_amdgcn_mfma_f32_16x16x32_bf16(afrag2[mi], bfrag[ni], acc[MF / 2 + mi][ni], 0, 0, 0);
        __builtin_amdgcn_s_setprio(0);
        MEMFENCE();
    }
}

// Grid (576 blocks, 512 thr) -- UNIFORM 128x256 tiles:
//   bids 0..63   : Q blocks   (16 m-tiles x 4 N-panels), launched first.
//   bids 64..575 : KV blocks  (64 m-tiles x 4 N-panels x {K,V}); A-panel consumers share bid%8.
__global__ __launch_bounds__(512, 4) void gemm_fused2(
    const bf16_t* __restrict__ Xq, const bf16_t* __restrict__ Xc,
    const bf16_t* __restrict__ wq, const bf16_t* __restrict__ wk, const bf16_t* __restrict__ wv,
    const float* __restrict__ bq, const float* __restrict__ bk, const float* __restrict__ bv,
    bf16_t* __restrict__ Qh, bf16_t* __restrict__ Kh, bf16_t* __restrict__ Vt) {
    __shared__ __align__(16) char smem[49152];
    const int bid  = blockIdx.x;
    const int tid  = threadIdx.x;
    const int w    = tid >> 6;
    const int lane = tid & 63;
    const int q4   = lane >> 4;
    const int c    = lane & 15;
    const int wm   = w >> 2;
    const int wn   = w & 3;
    (void)w;

    if (bid >= 64) {
        const int b     = bid - 64;
        const int r     = b & 7;          // XCD residue == m-tile low 3 bits
        const int j     = (b >> 3) & 7;   // {vmode, N-panel}
        const int mhi   = b >> 6;         // 0..7
        const int vmode = j >> 2;         // 0 = K, 1 = V
        const int n0    = (j & 3) * 256;
        const int m0    = (mhi * 8 + r) * 128;
        const bf16_t* W   = vmode ? wv : wk;
        const float* bias = vmode ? bv : bk;

        const int Nw = n0 + wn * 64;
        float bz[4];
#pragma unroll
        for (int ni = 0; ni < 4; ++ni) bz[ni] = bias[Nw + ni * 16 + c];
        MEMFENCE();

        f32x4 acc[4][4];
        gemm_core<4>(Xc, W, m0, n0, smem, acc);

        const int Mw = m0 + wm * 64;
        const int headbase = Nw >> 6;
        if (vmode == 0) {
#pragma unroll
            for (int mi = 0; mi < 4; ++mi) {
                const int mrow = Mw + mi * 16 + q4 * 4;
                const int nb2 = mrow >> 12, pos = mrow & 4095;
                bf16_t* ob = Kh + ((size_t)(nb2 * NHEAD + headbase) * TLEN + pos) * HD;
#pragma unroll
                for (int ni = 0; ni < 4; ++ni) {
                    const int d = ni * 16 + c;
#pragma unroll
                    for (int r2 = 0; r2 < 4; ++r2)
                        ob[(size_t)r2 * HD + d] = (bf16_t)(acc[mi][ni][r2] + bz[ni]);
                }
            }
        } else {
#pragma unroll
            for (int mi = 0; mi < 4; ++mi) {
                const int mrow = Mw + mi * 16 + q4 * 4;
                const int nb2 = mrow >> 12, pos = mrow & 4095;
                const int lin = (pos & ~31) + ((pos >> 2) & 3) * 8 + ((pos >> 4) & 1) * 4;
#pragma unroll
                for (int ni = 0; ni < 4; ++ni) {
                    const int d = ni * 16 + c;
                    bf16x4 v4;
#pragma unroll
                    for (int r2 = 0; r2 < 4; ++r2) v4[r2] = (bf16_t)(acc[mi][ni][r2] + bz[ni]);
                    *(bf16x4*)(Vt + ((size_t)(nb2 * NHEAD + headbase) * HD + d) * TLEN + lin) = v4;
                }
            }
        }
    } else {
        const int b  = bid;
        const int m0 = (b >> 2) * 128;
        const int n0 = (b & 3) * 256;

        const int Nw = n0 + wn * 64;
        float bz[4];
#pragma unroll
        for (int ni = 0; ni < 4; ++ni) bz[ni] = bq[Nw + ni * 16 + c];
        MEMFENCE();

        f32x4 acc[4][4];
        gemm_core<4>(Xq, wq, m0, n0, smem, acc);

        const int Mw = m0 + wm * 64;
        const int headbase = Nw >> 6;
#pragma unroll
        for (int mi = 0; mi < 4; ++mi) {
            const int mrow = Mw + mi * 16 + q4 * 4;
            const int nb2 = mrow >> 10, pos = mrow & 1023;
            bf16_t* ob = Qh + ((size_t)(nb2 * NHEAD + headbase) * XLEN + pos) * HD;
#pragma unroll
            for (int ni = 0; ni < 4; ++ni) {
                const int d = ni * 16 + c;
#pragma unroll
                for (int r2 = 0; r2 < 4; ++r2)
                    ob[(size_t)r2 * HD + d] = (bf16_t)((acc[mi][ni][r2] + bz[ni]) * CEXP);
            }
        }
    }
}

// ---------------- flash attention v5 (R5/R7-verified): 32 q-rows/wave, T/4 per block --------
__global__ __launch_bounds__(256, 4) void attn_kernel(const bf16_t* __restrict__ Qh,
                                                      const bf16_t* __restrict__ Kh,
                                                      const bf16_t* __restrict__ Vt,
                                                      bf16_t* __restrict__ Opart,
                                                      float* __restrict__ Lpart) {
    __shared__ __align__(16) char smem[32768];   // 2 bufs x (Kt 8KB | Vs 8KB); epilogue overlays

    const int tid  = threadIdx.x;
    const int lane = tid & 63;
    const int w    = tid >> 6;
    const int q4   = lane >> 4;
    const int c    = lane & 15;

    const int bid = blockIdx.x;
    const int xcd = bid & 7;
    const int seq = bid >> 3;           // 0..127
    const int tq  = seq & 3;
    const int xb  = (seq >> 2) & 7;
    const int g   = seq >> 5;           // 0..3
    const int nh  = g * 8 + xcd;
    const int xw  = xb * 128 + w * 32;

    const bf16_t* __restrict__ Kb = Kh + (size_t)nh * TLEN * HD;
    const bf16_t* __restrict__ Vb = Vt + (size_t)nh * HD * TLEN;

    // Q fragments (pre-scaled by CEXP in projection)
    bf16x8 qa[2][2];
#pragma unroll
    for (int mi = 0; mi < 2; ++mi) {
        const bf16_t* qr = Qh + ((size_t)nh * XLEN + xw + mi * 16 + c) * HD + q4 * 8;
        qa[mi][0] = *(const bf16x8*)(qr);
        qa[mi][1] = *(const bf16x8*)(qr + 32);
    }

    // staging geometry (XOR chunk swizzle)
    const int sRow0 = tid >> 3,  sRow1 = 32 + (tid >> 3);
    const int sCh   = tid & 7;
    const int kCol0 = ((sCh ^ (sRow0 & 7)) * 8);
    const int kCol1 = ((sCh ^ (sRow1 & 7)) * 8);

    // fragment read byte-offsets
    const int ofs0 = c * 128 + ((q4 ^ (c & 7)) * 16);
    const int ofs1 = c * 128 + (((4 + q4) ^ (c & 7)) * 16);

    f32x4 o[2][4];
#pragma unroll
    for (int i = 0; i < 2; ++i)
#pragma unroll
        for (int j = 0; j < 4; ++j) o[i][j] = (f32x4){0.f, 0.f, 0.f, 0.f};
    f32x4 lacc[2];
    lacc[0] = (f32x4){0.f, 0.f, 0.f, 0.f};
    lacc[1] = (f32x4){0.f, 0.f, 0.f, 0.f};

    bf16x8 ones8;
#pragma unroll
    for (int j = 0; j < 8; ++j) ones8[j] = (bf16_t)1.0f;

    const int t0base = tq * (TLEN / 4);

    // prologue: issue loads for stage 0 into buf 0
    {
        bf16_t* base = (bf16_t*)smem;
        __builtin_amdgcn_global_load_lds((glb_bf16*)(Kb + (size_t)(t0base + sRow0) * HD + kCol0), (lds_bf16*)(base + w * 512), 16, 0, 0);
        __builtin_amdgcn_global_load_lds((glb_bf16*)(Kb + (size_t)(t0base + sRow1) * HD + kCol1), (lds_bf16*)(base + 2048 + w * 512), 16, 0, 0);
        __builtin_amdgcn_global_load_lds((glb_bf16*)(Vb + (size_t)sRow0 * TLEN + t0base + kCol0), (lds_bf16*)(base + 4096 + w * 512), 16, 0, 0);
        __builtin_amdgcn_global_load_lds((glb_bf16*)(Vb + (size_t)sRow1 * TLEN + t0base + kCol1), (lds_bf16*)(base + 6144 + w * 512), 16, 0, 0);
    }

    for (int s = 0; s < 16; ++s) {
        __syncthreads();   // drains vmcnt -> stage s ready; prev compute reads done
        if (s < 15) {      // prefetch s+1 into the other buffer (lands during compute)
            const int t1 = t0base + (s + 1) * 64;
            bf16_t* base = (bf16_t*)smem + ((s + 1) & 1) * 8192;
            __builtin_amdgcn_global_load_lds((glb_bf16*)(Kb + (size_t)(t1 + sRow0) * HD + kCol0), (lds_bf16*)(base + w * 512), 16, 0, 0);
            __builtin_amdgcn_global_load_lds((glb_bf16*)(Kb + (size_t)(t1 + sRow1) * HD + kCol1), (lds_bf16*)(base + 2048 + w * 512), 16, 0, 0);
            __builtin_amdgcn_global_load_lds((glb_bf16*)(Vb + (size_t)sRow0 * TLEN + t1 + kCol0), (lds_bf16*)(base + 4096 + w * 512), 16, 0, 0);
            __builtin_amdgcn_global_load_lds((glb_bf16*)(Vb + (size_t)sRow1 * TLEN + t1 + kCol1), (lds_bf16*)(base + 6144 + w * 512), 16, 0, 0);
        }

        const char* KtB = smem + (s & 1) * 16384;
        const char* VsB = KtB + 8192;
#pragma unroll
        for (int g32 = 0; g32 < 2; ++g32) {
            // S^T = K·Q^T -> p8 per mi (k = q4*8 + tt*4 + r, matching V's t-perm)
            bf16x8 p8[2];
#pragma unroll
            for (int tt = 0; tt < 2; ++tt) {
                const int rofs = g32 * 4096 + tt * 2048;
                bf16x8 kb0 = *(const bf16x8*)(KtB + rofs + ofs0);
                bf16x8 kb1 = *(const bf16x8*)(KtB + rofs + ofs1);
#pragma unroll
                for (int mi = 0; mi < 2; ++mi) {
                    f32x4 sv = (f32x4){0.f, 0.f, 0.f, 0.f};
                    sv = __builtin_amdgcn_mfma_f32_16x16x32_bf16(kb0, qa[mi][0], sv, 0, 0, 0);
                    sv = __builtin_amdgcn_mfma_f32_16x16x32_bf16(kb1, qa[mi][1], sv, 0, 0, 0);
#pragma unroll
                    for (int r = 0; r < 4; ++r)
                        p8[mi][tt * 4 + r] = (bf16_t)__builtin_exp2f(sv[r]);
                }
            }
            // O += P V at K=32 (V A-fragment is one contiguous b128)
            const int vsel = g32 ? ofs1 : ofs0;
            bf16x8 va[4];
#pragma unroll
            for (int dt = 0; dt < 4; ++dt)
                va[dt] = *(const bf16x8*)(VsB + vsel + dt * 2048);
#pragma unroll
            for (int mi = 0; mi < 2; ++mi) {
#pragma unroll
                for (int dt = 0; dt < 4; ++dt)
                    o[mi][dt] = __builtin_amdgcn_mfma_f32_16x16x32_bf16(va[dt], p8[mi], o[mi][dt], 0, 0, 0);
                lacc[mi] = __builtin_amdgcn_mfma_f32_16x16x32_bf16(ones8, p8[mi], lacc[mi], 0, 0, 0);
            }
        }
    }

    // ---- epilogue: overlay LDS, transpose, write partials ----
    __syncthreads();
    bf16_t* Ob = (bf16_t*)smem;                 // [w][64 d][33 m]
    float*  Lb = (float*)(smem + 16896);        // [w][32]
#pragma unroll
    for (int mi = 0; mi < 2; ++mi) {
        if (q4 == 0) Lb[w * 32 + mi * 16 + c] = lacc[mi][0];
#pragma unroll
        for (int dt = 0; dt < 4; ++dt)
#pragma unroll
            for (int r = 0; r < 4; ++r)
                Ob[w * 2112 + (dt * 16 + q4 * 4 + r) * 33 + mi * 16 + c] = (bf16_t)o[mi][dt][r];
    }
    // wave-internal DS ordering: no barrier needed for own slab
    {
        const int lr = lane >> 1;               // row 0..31
        const int dh = lane & 1;                // d half
        bf16x8 out4[4];
#pragma unroll
        for (int j2 = 0; j2 < 4; ++j2)
#pragma unroll
            for (int e = 0; e < 8; ++e)
                out4[j2][e] = Ob[w * 2112 + (dh * 32 + j2 * 8 + e) * 33 + lr];
        const size_t pair = (size_t)nh * XLEN + xw + lr;
        bf16_t* op = Opart + (pair * 4 + tq) * HD + dh * 32;
#pragma unroll
        for (int j2 = 0; j2 < 4; ++j2)
            *(bf16x8*)(op + j2 * 8) = out4[j2];
        if (dh == 0) Lpart[pair * 4 + tq] = Lb[w * 32 + lr];
    }
}

// ---------------- merge 4 T-quarter partials, normalize, write fp32 ----------------
__global__ __launch_bounds__(256) void attn_merge(const bf16_t* __restrict__ Opart,
                                                  const float* __restrict__ Lpart,
                                                  float* __restrict__ Out) {
    const int u    = blockIdx.x * 256 + threadIdx.x;
    const int pair = u >> 3;              // nh*1024 + x
    const int d0   = (u & 7) * 8;
    const int nh   = pair >> 10;
    const int x    = pair & 1023;
    const int n    = nh >> 4;
    const int h    = nh & 15;

    float l = 0.f;
    float s[8];
#pragma unroll
    for (int j = 0; j < 8; ++j) s[j] = 0.f;
#pragma unroll
    for (int tqi = 0; tqi < 4; ++tqi) {
        l += Lpart[pair * 4 + tqi];
        bf16x8 v = *(const bf16x8*)(Opart + ((size_t)pair * 4 + tqi) * HD + d0);
#pragma unroll
        for (int j = 0; j < 8; ++j) s[j] += (float)v[j];
    }
    const float inv = 1.0f / l;
    f32x4 v0, v1;
#pragma unroll
    for (int j = 0; j < 4; ++j) { v0[j] = s[j] * inv; v1[j] = s[4 + j] * inv; }
    float* op = Out + ((size_t)(n * XLEN + x)) * D_MODEL + h * HD + d0;
    *(f32x4*)(op)     = v0;
    *(f32x4*)(op + 4) = v1;
}

extern "C" void kernel_launch(void* const* d_in, const int* in_sizes, int n_in,
                              void* d_out, int out_size, void* d_ws, size_t ws_size,
                              hipStream_t stream) {
    (void)in_sizes; (void)n_in; (void)out_size; (void)ws_size;
    const float* prev = (const float*)d_in[0];
    const float* ctx  = (const float*)d_in[1];
    const float* Wq   = (const float*)d_in[2];
    const float* bq   = (const float*)d_in[3];
    const float* Wk   = (const float*)d_in[4];
    const float* bk   = (const float*)d_in[5];
    const float* Wv   = (const float*)d_in[6];
    const float* bv   = (const float*)d_in[7];

    const size_t MiB = 1024 * 1024;
    char* ws = (char*)d_ws;
    bf16_t* prev_b = (bf16_t*)(ws);                //  4 MiB -- dead after gemm -> Lpart
    bf16_t* ctx_b  = (bf16_t*)(ws + 4 * MiB);      // 16 MiB -- dead after gemm -> Opart
    bf16_t* wq_b   = (bf16_t*)(ws + 20 * MiB);     //  2 MiB
    bf16_t* wk_b   = (bf16_t*)(ws + 22 * MiB);     //  2 MiB
    bf16_t* wv_b   = (bf16_t*)(ws + 24 * MiB);     //  2 MiB
    bf16_t* Qh     = (bf16_t*)(ws + 26 * MiB);     //  4 MiB
    bf16_t* Kh     = (bf16_t*)(ws + 30 * MiB);     // 16 MiB
    bf16_t* Vt     = (bf16_t*)(ws + 46 * MiB);     // 16 MiB (total 62 MiB)
    bf16_t* Opart  = ctx_b;                        // 16 MiB overlay
    float*  Lpart  = (float*)prev_b;               // 512 KiB overlay

    convert5<<<1664, 256, 0, stream>>>(prev, ctx, Wq, Wk, Wv, prev_b, ctx_b, wq_b, wk_b, wv_b);
    gemm_fused2<<<576, 512, 0, stream>>>(prev_b, ctx_b, wq_b, wk_b, wv_b, bq, bk, bv, Qh, Kh, Vt);
    attn_kernel<<<1024, 256, 0, stream>>>(Qh, Kh, Vt, Opart, Lpart);
    attn_merge<<<1024, 256, 0, stream>>>(Opart, Lpart, (float*)d_out);
}

// Round 11
// 202.585 us; speedup vs baseline: 1.0436x; 1.0436x over previous
//
#include <hip/hip_runtime.h>

typedef __bf16 bf16_t;
typedef __bf16 bf16x8 __attribute__((ext_vector_type(8)));
typedef __bf16 bf16x4 __attribute__((ext_vector_type(4)));
typedef float f32x4 __attribute__((ext_vector_type(4)));

#define D_MODEL 1024
#define NHEAD 16
#define HD 64
#define XLEN 1024
#define TLEN 4096
#define NBATCH 2
#define CEXP 0.18033688011112042f /* log2(e)/sqrt(64) */

typedef __attribute__((address_space(3))) bf16_t lds_bf16;
typedef const __attribute__((address_space(1))) bf16_t glb_bf16;

#define MEMFENCE() asm volatile("" ::: "memory")

// ---------------- convert: fp32 -> bf16, 5 arrays in one launch ----------------
__global__ __launch_bounds__(256) void convert5(const float* __restrict__ prev, const float* __restrict__ ctx,
                                                const float* __restrict__ wq, const float* __restrict__ wk,
                                                const float* __restrict__ wv,
                                                bf16_t* __restrict__ prev_b, bf16_t* __restrict__ ctx_b,
                                                bf16_t* __restrict__ wq_b, bf16_t* __restrict__ wk_b,
                                                bf16_t* __restrict__ wv_b) {
    int b = blockIdx.x;
    const float* src; bf16_t* dst; int lb;
    if (b < 256)       { src = prev; dst = prev_b; lb = b; }
    else if (b < 1280) { src = ctx;  dst = ctx_b;  lb = b - 256; }
    else if (b < 1408) { src = wq;   dst = wq_b;   lb = b - 1280; }
    else if (b < 1536) { src = wk;   dst = wk_b;   lb = b - 1408; }
    else               { src = wv;   dst = wv_b;   lb = b - 1536; }
    const int base = lb * 8192 + threadIdx.x * 4;
#pragma unroll
    for (int i = 0; i < 8; ++i) {
        const int off = base + i * 1024;
        f32x4 f = *(const f32x4*)(src + off);
        bf16x4 h;
        h[0] = (bf16_t)f[0]; h[1] = (bf16_t)f[1]; h[2] = (bf16_t)f[2]; h[3] = (bf16_t)f[3];
        *(bf16x4*)(dst + off) = h;
    }
}

// ---------------- Q-path GEMM core: BK=64, ring-2, 2-phase (R5-verified), MF=4 ----------------
template<int MF>   // MF=4: BM=128, BN=256
__device__ __forceinline__ void gemm_core(const bf16_t* __restrict__ Xa,
                                          const bf16_t* __restrict__ Wb,
                                          int m0, int n0, char* smem,
                                          f32x4 (&acc)[MF][4]) {
    const int tid  = threadIdx.x;
    const int w    = tid >> 6;
    const int lane = tid & 63;
    const int q4   = lane >> 4;
    const int c    = lane & 15;
    const int wm   = w >> 2;
    const int wn   = w & 3;

    constexpr int ABYTES = MF * 4096;
    constexpr int BUFSZ  = ABYTES + 32768;
    constexpr int AI     = MF / 4;
    constexpr int NT     = 16;

#pragma unroll
    for (int i = 0; i < MF; ++i)
#pragma unroll
        for (int j = 0; j < 4; ++j) acc[i][j] = (f32x4){0.f, 0.f, 0.f, 0.f};

    const int xp = ((lane & 3) * 16) ^ (((lane >> 5) & 1) << 5);
    const char* gA = (const char*)Xa + ((size_t)(m0 + w * 16 + (lane >> 2)) << 11) + xp;
    const char* gB = (const char*)Wb + ((size_t)(n0 + w * 16 + (lane >> 2)) << 11) + xp;
    char* lw = smem + w * 1024;
    const int fo = c * 64 + ((q4 * 16) ^ (((c >> 3) & 1) << 5));

#pragma unroll
    for (int i = 0; i < AI; ++i)
#pragma unroll
        for (int k = 0; k < 2; ++k)
            __builtin_amdgcn_global_load_lds((glb_bf16*)(gA + (size_t)i * 262144 + k * 64),
                                             (lds_bf16*)(lw + k * (MF * 2048) + i * 8192), 16, 0, 0);
#pragma unroll
    for (int i = 0; i < 2; ++i)
#pragma unroll
        for (int k = 0; k < 2; ++k)
            __builtin_amdgcn_global_load_lds((glb_bf16*)(gB + (size_t)i * 262144 + k * 64),
                                             (lds_bf16*)(lw + ABYTES + k * 16384 + i * 8192), 16, 0, 0);
    MEMFENCE();

#pragma unroll 1
    for (int t = 0; t < NT; ++t) {
        asm volatile("s_waitcnt vmcnt(0)" ::: "memory");
        __builtin_amdgcn_s_barrier();
        MEMFENCE();

        if (t + 1 < NT) {
            char* pb = lw + ((t + 1) & 1) * BUFSZ;
            const size_t tk = (size_t)(t + 1) * 128;
#pragma unroll
            for (int i = 0; i < AI; ++i)
#pragma unroll
                for (int k = 0; k < 2; ++k)
                    __builtin_amdgcn_global_load_lds((glb_bf16*)(gA + (size_t)i * 262144 + tk + k * 64),
                                                     (lds_bf16*)(pb + k * (MF * 2048) + i * 8192), 16, 0, 0);
#pragma unroll
            for (int i = 0; i < 2; ++i)
#pragma unroll
                for (int k = 0; k < 2; ++k)
                    __builtin_amdgcn_global_load_lds((glb_bf16*)(gB + (size_t)i * 262144 + tk + k * 64),
                                                     (lds_bf16*)(pb + ABYTES + k * 16384 + i * 8192), 16, 0, 0);
        }

        const char* cb = smem + (t & 1) * BUFSZ;
#pragma unroll
        for (int kk = 0; kk < 2; ++kk) {
            bf16x8 bfrag[4];
#pragma unroll
            for (int ni = 0; ni < 4; ++ni)
                bfrag[ni] = *(const bf16x8*)(cb + ABYTES + kk * 16384 + (wn * 4 + ni) * 1024 + fo);
            bf16x8 afrag[MF / 2];
#pragma unroll
            for (int mi = 0; mi < MF / 2; ++mi)
                afrag[mi] = *(const bf16x8*)(cb + kk * (MF * 2048) + (wm * MF + mi) * 1024 + fo);
            __builtin_amdgcn_s_setprio(1);
#pragma unroll
            for (int mi = 0; mi < MF / 2; ++mi)
#pragma unroll
                for (int ni = 0; ni < 4; ++ni)
                    acc[mi][ni] = __builtin_amdgcn_mfma_f32_16x16x32_bf16(afrag[mi], bfrag[ni], acc[mi][ni], 0, 0, 0);
            __builtin_amdgcn_s_setprio(0);

            bf16x8 afrag2[MF / 2];
#pragma unroll
            for (int mi = 0; mi < MF / 2; ++mi)
                afrag2[mi] = *(const bf16x8*)(cb + kk * (MF * 2048) + (wm * MF + MF / 2 + mi) * 1024 + fo);
            __builtin_amdgcn_s_setprio(1);
#pragma unroll
            for (int mi = 0; mi < MF / 2; ++mi)
#pragma unroll
                for (int ni = 0; ni < 4; ++ni)
                    acc[MF / 2 + mi][ni] = __builtin_amdgcn_mfma_f32_16x16x32_bf16(afrag2[mi], bfrag[ni], acc[MF / 2 + mi][ni], 0, 0, 0);
            __builtin_amdgcn_s_setprio(0);
            MEMFENCE();
        }
    }
}

// ---------------- KV-path GEMM core: 256x256, BK=64, 4-phase/K-tile with counted vmcnt ----------
// LDS per buf (64KB): A halves (2x16KB: rows 0-127,128-255) then B halves; dbuf=2 -> 128KB.
// Half = 16 subtiles of 16x32 bf16 (st_16x32 swizzle; pre-swizzled global source, swizzled read).
// Phases per tile t (buf b=t&1): ph1 reads A m0-3 + B n0-1, stages H(t+1,1); ph2 reads B n2-3,
// stages H(t+1,2); ph3 reads A m4-7, stages H(t+1,3); ph4 (no reads) stages H(t+2,0) [buf b --
// safe: all buf-b reads retired by ph3-end barrier], then vmcnt(2) gate for tile t+1 (H(t+2,0)
// stays in flight; vmcnt(0) only at t=NT-2). 16 MFMA per phase wrapped in setprio (T5).
// R10 BUG (fixed): STAGE had a bogus +(j&2)*131072 (= +128 rows) on the B half-tiles -- B
// staged the wrong weight rows (absmax 0.81). Row-half offset is (j&1)*262144 ONLY.
__device__ __forceinline__ void gemm_core8(const bf16_t* __restrict__ Xa,
                                           const bf16_t* __restrict__ Wb,
                                           int m0, int n0, char* smem,
                                           f32x4 (&acc)[8][4]) {
    const int tid  = threadIdx.x;
    const int w    = tid >> 6;
    const int lane = tid & 63;
    const int q4   = lane >> 4;
    const int c    = lane & 15;
    const int wm   = w >> 2;     // 0..1 : 128-row half
    const int wn   = w & 3;      // 0..3 : 64-col group
    constexpr int NT = 16;

#pragma unroll
    for (int i = 0; i < 8; ++i)
#pragma unroll
        for (int j = 0; j < 4; ++j) acc[i][j] = (f32x4){0.f, 0.f, 0.f, 0.f};

    // staging source (per-lane, pre-swizzled): wave w stages subtiles w and w+8 of a half:
    // rows (w>>1)*16+rr (rr=lane>>2), K-col-half (w&1); 16B chunk lane&3, st_16x32 xor.
    const int rr = lane >> 2;
    const int xp = ((lane & 3) * 16) ^ (((rr >> 3) & 1) << 5);
    const char* gA = (const char*)Xa + ((size_t)(m0 + (w >> 1) * 16 + rr) << 11) + (w & 1) * 64 + xp;
    const char* gB = (const char*)Wb + ((size_t)(n0 + (w >> 1) * 16 + rr) << 11) + (w & 1) * 64 + xp;

    // fragment read offset within a subtile
    const int fo = c * 64 + ((q4 * 16) ^ (((c >> 3) & 1) << 5));

    // stage half-tile j (0:A rows0-127, 1:A rows128-255, 2:B rows0-127, 3:B rows128-255)
    // of K-tile 'tile' (2 global_load_lds; instr2 = +64 rows = subtile +8).
    auto STAGE = [&](int tile, int j) {
        const size_t kb = (size_t)tile * 128;
        const char* g = ((j < 2) ? gA : gB) + (size_t)(j & 1) * 262144 + kb;
        char* l = smem + (tile & 1) * 65536 + ((j < 2) ? 0 : 32768) + (j & 1) * 16384 + w * 1024;
        __builtin_amdgcn_global_load_lds((glb_bf16*)(g),          (lds_bf16*)(l),        16, 0, 0);
        __builtin_amdgcn_global_load_lds((glb_bf16*)(g + 131072), (lds_bf16*)(l + 8192), 16, 0, 0);
    };

    // prologue: tile0 fully + H(1,0); gate (10 issued, wait-to-2 -> tile0's 8 landed)
    STAGE(0, 0); STAGE(0, 1); STAGE(0, 2); STAGE(0, 3); STAGE(1, 0);
    MEMFENCE();
    asm volatile("s_waitcnt vmcnt(2)" ::: "memory");
    __builtin_amdgcn_s_barrier();
    MEMFENCE();

#pragma unroll 1
    for (int t = 0; t < NT; ++t) {
        const char* cb = smem + (t & 1) * 65536;
        const char* Ab = cb + wm * 16384;
        const char* Bb = cb + 32768 + (wn >> 1) * 16384 + (wn & 1) * 8192;

        bf16x8 a[4][2], b0[2][2], b1[2][2];

        // ---- phase 1: read A m0-3 (8) + B n0-1 (4); stage H(t+1,1); 16 MFMA ----
#pragma unroll
        for (int mi = 0; mi < 4; ++mi)
#pragma unroll
            for (int kh = 0; kh < 2; ++kh)
                a[mi][kh] = *(const bf16x8*)(Ab + (mi * 2 + kh) * 1024 + fo);
#pragma unroll
        for (int ni = 0; ni < 2; ++ni)
#pragma unroll
            for (int kh = 0; kh < 2; ++kh)
                b0[ni][kh] = *(const bf16x8*)(Bb + (ni * 2 + kh) * 1024 + fo);
        if (t + 1 < NT) STAGE(t + 1, 1);
        __builtin_amdgcn_s_barrier();
        MEMFENCE();
        __builtin_amdgcn_s_setprio(1);
#pragma unroll
        for (int mi = 0; mi < 4; ++mi)
#pragma unroll
            for (int ni = 0; ni < 2; ++ni)
#pragma unroll
                for (int kh = 0; kh < 2; ++kh)
                    acc[mi][ni] = __builtin_amdgcn_mfma_f32_16x16x32_bf16(a[mi][kh], b0[ni][kh], acc[mi][ni], 0, 0, 0);
        __builtin_amdgcn_s_setprio(0);
        MEMFENCE();
        __builtin_amdgcn_s_barrier();

        // ---- phase 2: read B n2-3 (4); stage H(t+1,2); 16 MFMA ----
#pragma unroll
        for (int ni = 0; ni < 2; ++ni)
#pragma unroll
            for (int kh = 0; kh < 2; ++kh)
                b1[ni][kh] = *(const bf16x8*)(Bb + ((2 + ni) * 2 + kh) * 1024 + fo);
        if (t + 1 < NT) STAGE(t + 1, 2);
        __builtin_amdgcn_s_barrier();
        MEMFENCE();
        __builtin_amdgcn_s_setprio(1);
#pragma unroll
        for (int mi = 0; mi < 4; ++mi)
#pragma unroll
            for (int ni = 0; ni < 2; ++ni)
#pragma unroll
                for (int kh = 0; kh < 2; ++kh)
                    acc[mi][2 + ni] = __builtin_amdgcn_mfma_f32_16x16x32_bf16(a[mi][kh], b1[ni][kh], acc[mi][2 + ni], 0, 0, 0);
        __builtin_amdgcn_s_setprio(0);
        MEMFENCE();
        __builtin_amdgcn_s_barrier();

        // ---- phase 3: read A m4-7 (8, reuse regs); stage H(t+1,3); 16 MFMA (B n0-1 held) ----
#pragma unroll
        for (int mi = 0; mi < 4; ++mi)
#pragma unroll
            for (int kh = 0; kh < 2; ++kh)
                a[mi][kh] = *(const bf16x8*)(Ab + ((4 + mi) * 2 + kh) * 1024 + fo);
        if (t + 1 < NT) STAGE(t + 1, 3);
        __builtin_amdgcn_s_barrier();
        MEMFENCE();
        __builtin_amdgcn_s_setprio(1);
#pragma unroll
        for (int mi = 0; mi < 4; ++mi)
#pragma unroll
            for (int ni = 0; ni < 2; ++ni)
#pragma unroll
                for (int kh = 0; kh < 2; ++kh)
                    acc[4 + mi][ni] = __builtin_amdgcn_mfma_f32_16x16x32_bf16(a[mi][kh], b0[ni][kh], acc[4 + mi][ni], 0, 0, 0);
        __builtin_amdgcn_s_setprio(0);
        MEMFENCE();
        __builtin_amdgcn_s_barrier();

        // ---- phase 4: no reads; stage H(t+2,0) (buf b: reads retired at ph3-end barrier);
        //      16 MFMA; vmcnt gate for tile t+1 ----
        if (t + 2 < NT) STAGE(t + 2, 0);
        __builtin_amdgcn_s_barrier();
        MEMFENCE();
        __builtin_amdgcn_s_setprio(1);
#pragma unroll
        for (int mi = 0; mi < 4; ++mi)
#pragma unroll
            for (int ni = 0; ni < 2; ++ni)
#pragma unroll
                for (int kh = 0; kh < 2; ++kh)
                    acc[4 + mi][2 + ni] = __builtin_amdgcn_mfma_f32_16x16x32_bf16(a[mi][kh], b1[ni][kh], acc[4 + mi][2 + ni], 0, 0, 0);
        __builtin_amdgcn_s_setprio(0);
        MEMFENCE();
        if (t + 1 < NT) {
            if (t + 2 < NT) asm volatile("s_waitcnt vmcnt(2)" ::: "memory");
            else            asm volatile("s_waitcnt vmcnt(0)" ::: "memory");
        }
        __builtin_amdgcn_s_barrier();
        MEMFENCE();
    }
}

// Grid (320 blocks, 512 thr):
//   bids 0..63   : Q blocks (BM=128, BN=256, 2-phase core) -- launched FIRST (short tail work).
//   bids 64..319 : KV blocks (256x256, 4-phase core) = exactly 256 = one clean round.
//                  All 8 jobs {4 N-panels x K,V} of one A-panel share bid%8 -> same XCD.
__global__ __launch_bounds__(512, 2) void gemm_fused2(
    const bf16_t* __restrict__ Xq, const bf16_t* __restrict__ Xc,
    const bf16_t* __restrict__ wq, const bf16_t* __restrict__ wk, const bf16_t* __restrict__ wv,
    const float* __restrict__ bq, const float* __restrict__ bk, const float* __restrict__ bv,
    bf16_t* __restrict__ Qh, bf16_t* __restrict__ Kh, bf16_t* __restrict__ Vt) {
    __shared__ __align__(16) char smem[131072];
    const int bid  = blockIdx.x;
    const int tid  = threadIdx.x;
    const int w    = tid >> 6;
    const int lane = tid & 63;
    const int q4   = lane >> 4;
    const int c    = lane & 15;
    const int wm   = w >> 2;
    const int wn   = w & 3;
    (void)w;

    if (bid >= 64) {
        const int b     = bid - 64;
        const int r     = b & 7;          // XCD residue == m-tile low 3 bits
        const int j     = (b >> 3) & 7;   // {vmode, N-panel}
        const int mhi   = b >> 6;         // 0..3
        const int vmode = j >> 2;         // 0 = K, 1 = V
        const int n0    = (j & 3) * 256;
        const int m0    = (mhi * 8 + r) * 256;
        const bf16_t* W   = vmode ? wv : wk;
        const float* bias = vmode ? bv : bk;

        const int Nw = n0 + wn * 64;
        float bz[4];
#pragma unroll
        for (int ni = 0; ni < 4; ++ni) bz[ni] = bias[Nw + ni * 16 + c];
        MEMFENCE();

        f32x4 acc[8][4];
        gemm_core8(Xc, W, m0, n0, smem, acc);

        const int Mw = m0 + wm * 128;
        const int headbase = Nw >> 6;
        if (vmode == 0) {
#pragma unroll
            for (int mi = 0; mi < 8; ++mi) {
                const int mrow = Mw + mi * 16 + q4 * 4;
                const int nb2 = mrow >> 12, pos = mrow & 4095;
                bf16_t* ob = Kh + ((size_t)(nb2 * NHEAD + headbase) * TLEN + pos) * HD;
#pragma unroll
                for (int ni = 0; ni < 4; ++ni) {
                    const int d = ni * 16 + c;
#pragma unroll
                    for (int r2 = 0; r2 < 4; ++r2)
                        ob[(size_t)r2 * HD + d] = (bf16_t)(acc[mi][ni][r2] + bz[ni]);
                }
            }
        } else {
#pragma unroll
            for (int mi = 0; mi < 8; ++mi) {
                const int mrow = Mw + mi * 16 + q4 * 4;
                const int nb2 = mrow >> 12, pos = mrow & 4095;
                const int lin = (pos & ~31) + ((pos >> 2) & 3) * 8 + ((pos >> 4) & 1) * 4;
#pragma unroll
                for (int ni = 0; ni < 4; ++ni) {
                    const int d = ni * 16 + c;
                    bf16x4 v4;
#pragma unroll
                    for (int r2 = 0; r2 < 4; ++r2) v4[r2] = (bf16_t)(acc[mi][ni][r2] + bz[ni]);
                    *(bf16x4*)(Vt + ((size_t)(nb2 * NHEAD + headbase) * HD + d) * TLEN + lin) = v4;
                }
            }
        }
    } else {
        const int b  = bid;
        const int m0 = (b >> 2) * 128;
        const int n0 = (b & 3) * 256;

        const int Nw = n0 + wn * 64;
        float bz[4];
#pragma unroll
        for (int ni = 0; ni < 4; ++ni) bz[ni] = bq[Nw + ni * 16 + c];
        MEMFENCE();

        f32x4 acc[4][4];
        gemm_core<4>(Xq, wq, m0, n0, smem, acc);

        const int Mw = m0 + wm * 64;
        const int headbase = Nw >> 6;
#pragma unroll
        for (int mi = 0; mi < 4; ++mi) {
            const int mrow = Mw + mi * 16 + q4 * 4;
            const int nb2 = mrow >> 10, pos = mrow & 1023;
            bf16_t* ob = Qh + ((size_t)(nb2 * NHEAD + headbase) * XLEN + pos) * HD;
#pragma unroll
            for (int ni = 0; ni < 4; ++ni) {
                const int d = ni * 16 + c;
#pragma unroll
                for (int r2 = 0; r2 < 4; ++r2)
                    ob[(size_t)r2 * HD + d] = (bf16_t)((acc[mi][ni][r2] + bz[ni]) * CEXP);
            }
        }
    }
}

// ---------------- flash attention v5 (R5-verified): 32 q-rows/wave, T/4 per block ----------------
__global__ __launch_bounds__(256, 4) void attn_kernel(const bf16_t* __restrict__ Qh,
                                                      const bf16_t* __restrict__ Kh,
                                                      const bf16_t* __restrict__ Vt,
                                                      bf16_t* __restrict__ Opart,
                                                      float* __restrict__ Lpart) {
    __shared__ __align__(16) char smem[32768];

    const int tid  = threadIdx.x;
    const int lane = tid & 63;
    const int w    = tid >> 6;
    const int q4   = lane >> 4;
    const int c    = lane & 15;

    const int bid = blockIdx.x;
    const int xcd = bid & 7;
    const int seq = bid >> 3;           // 0..127
    const int tq  = seq & 3;
    const int xb  = (seq >> 2) & 7;
    const int g   = seq >> 5;           // 0..3
    const int nh  = g * 8 + xcd;
    const int xw  = xb * 128 + w * 32;

    const bf16_t* __restrict__ Kb = Kh + (size_t)nh * TLEN * HD;
    const bf16_t* __restrict__ Vb = Vt + (size_t)nh * HD * TLEN;

    bf16x8 qa[2][2];
#pragma unroll
    for (int mi = 0; mi < 2; ++mi) {
        const bf16_t* qr = Qh + ((size_t)nh * XLEN + xw + mi * 16 + c) * HD + q4 * 8;
        qa[mi][0] = *(const bf16x8*)(qr);
        qa[mi][1] = *(const bf16x8*)(qr + 32);
    }

    const int sRow0 = tid >> 3,  sRow1 = 32 + (tid >> 3);
    const int sCh   = tid & 7;
    const int kCol0 = ((sCh ^ (sRow0 & 7)) * 8);
    const int kCol1 = ((sCh ^ (sRow1 & 7)) * 8);

    const int ofs0 = c * 128 + ((q4 ^ (c & 7)) * 16);
    const int ofs1 = c * 128 + (((4 + q4) ^ (c & 7)) * 16);

    f32x4 o[2][4];
#pragma unroll
    for (int i = 0; i < 2; ++i)
#pragma unroll
        for (int j = 0; j < 4; ++j) o[i][j] = (f32x4){0.f, 0.f, 0.f, 0.f};
    f32x4 lacc[2];
    lacc[0] = (f32x4){0.f, 0.f, 0.f, 0.f};
    lacc[1] = (f32x4){0.f, 0.f, 0.f, 0.f};

    bf16x8 ones8;
#pragma unroll
    for (int j = 0; j < 8; ++j) ones8[j] = (bf16_t)1.0f;

    const int t0base = tq * (TLEN / 4);

    {
        bf16_t* base = (bf16_t*)smem;
        __builtin_amdgcn_global_load_lds((glb_bf16*)(Kb + (size_t)(t0base + sRow0) * HD + kCol0), (lds_bf16*)(base + w * 512), 16, 0, 0);
        __builtin_amdgcn_global_load_lds((glb_bf16*)(Kb + (size_t)(t0base + sRow1) * HD + kCol1), (lds_bf16*)(base + 2048 + w * 512), 16, 0, 0);
        __builtin_amdgcn_global_load_lds((glb_bf16*)(Vb + (size_t)sRow0 * TLEN + t0base + kCol0), (lds_bf16*)(base + 4096 + w * 512), 16, 0, 0);
        __builtin_amdgcn_global_load_lds((glb_bf16*)(Vb + (size_t)sRow1 * TLEN + t0base + kCol1), (lds_bf16*)(base + 6144 + w * 512), 16, 0, 0);
    }

    for (int s = 0; s < 16; ++s) {
        __syncthreads();
        if (s < 15) {
            const int t1 = t0base + (s + 1) * 64;
            bf16_t* base = (bf16_t*)smem + ((s + 1) & 1) * 8192;
            __builtin_amdgcn_global_load_lds((glb_bf16*)(Kb + (size_t)(t1 + sRow0) * HD + kCol0), (lds_bf16*)(base + w * 512), 16, 0, 0);
            __builtin_amdgcn_global_load_lds((glb_bf16*)(Kb + (size_t)(t1 + sRow1) * HD + kCol1), (lds_bf16*)(base + 2048 + w * 512), 16, 0, 0);
            __builtin_amdgcn_global_load_lds((glb_bf16*)(Vb + (size_t)sRow0 * TLEN + t1 + kCol0), (lds_bf16*)(base + 4096 + w * 512), 16, 0, 0);
            __builtin_amdgcn_global_load_lds((glb_bf16*)(Vb + (size_t)sRow1 * TLEN + t1 + kCol1), (lds_bf16*)(base + 6144 + w * 512), 16, 0, 0);
        }

        const char* KtB = smem + (s & 1) * 16384;
        const char* VsB = KtB + 8192;
#pragma unroll
        for (int g32 = 0; g32 < 2; ++g32) {
            bf16x8 p8[2];
#pragma unroll
            for (int tt = 0; tt < 2; ++tt) {
                const int rofs = g32 * 4096 + tt * 2048;
                bf16x8 kb0 = *(const bf16x8*)(KtB + rofs + ofs0);
                bf16x8 kb1 = *(const bf16x8*)(KtB + rofs + ofs1);
#pragma unroll
                for (int mi = 0; mi < 2; ++mi) {
                    f32x4 sv = (f32x4){0.f, 0.f, 0.f, 0.f};
                    sv = __builtin_amdgcn_mfma_f32_16x16x32_bf16(kb0, qa[mi][0], sv, 0, 0, 0);
                    sv = __builtin_amdgcn_mfma_f32_16x16x32_bf16(kb1, qa[mi][1], sv, 0, 0, 0);
#pragma unroll
                    for (int r = 0; r < 4; ++r)
                        p8[mi][tt * 4 + r] = (bf16_t)__builtin_exp2f(sv[r]);
                }
            }
            const int vsel = g32 ? ofs1 : ofs0;
            bf16x8 va[4];
#pragma unroll
            for (int dt = 0; dt < 4; ++dt)
                va[dt] = *(const bf16x8*)(VsB + vsel + dt * 2048);
#pragma unroll
            for (int mi = 0; mi < 2; ++mi) {
#pragma unroll
                for (int dt = 0; dt < 4; ++dt)
                    o[mi][dt] = __builtin_amdgcn_mfma_f32_16x16x32_bf16(va[dt], p8[mi], o[mi][dt], 0, 0, 0);
                lacc[mi] = __builtin_amdgcn_mfma_f32_16x16x32_bf16(ones8, p8[mi], lacc[mi], 0, 0, 0);
            }
        }
    }

    __syncthreads();
    bf16_t* Ob = (bf16_t*)smem;
    float*  Lb = (float*)(smem + 16896);
#pragma unroll
    for (int mi = 0; mi < 2; ++mi) {
        if (q4 == 0) Lb[w * 32 + mi * 16 + c] = lacc[mi][0];
#pragma unroll
        for (int dt = 0; dt < 4; ++dt)
#pragma unroll
            for (int r = 0; r < 4; ++r)
                Ob[w * 2112 + (dt * 16 + q4 * 4 + r) * 33 + mi * 16 + c] = (bf16_t)o[mi][dt][r];
    }
    {
        const int lr = lane >> 1;
        const int dh = lane & 1;
        bf16x8 out4[4];
#pragma unroll
        for (int j2 = 0; j2 < 4; ++j2)
#pragma unroll
            for (int e = 0; e < 8; ++e)
                out4[j2][e] = Ob[w * 2112 + (dh * 32 + j2 * 8 + e) * 33 + lr];
        const size_t pair = (size_t)nh * XLEN + xw + lr;
        bf16_t* op = Opart + (pair * 4 + tq) * HD + dh * 32;
#pragma unroll
        for (int j2 = 0; j2 < 4; ++j2)
            *(bf16x8*)(op + j2 * 8) = out4[j2];
        if (dh == 0) Lpart[pair * 4 + tq] = Lb[w * 32 + lr];
    }
}

// ---------------- merge 4 T-quarter partials, normalize, write fp32 ----------------
__global__ __launch_bounds__(256) void attn_merge(const bf16_t* __restrict__ Opart,
                                                  const float* __restrict__ Lpart,
                                                  float* __restrict__ Out) {
    const int u    = blockIdx.x * 256 + threadIdx.x;
    const int pair = u >> 3;
    const int d0   = (u & 7) * 8;
    const int nh   = pair >> 10;
    const int x    = pair & 1023;
    const int n    = nh >> 4;
    const int h    = nh & 15;

    float l = 0.f;
    float s[8];
#pragma unroll
    for (int j = 0; j < 8; ++j) s[j] = 0.f;
#pragma unroll
    for (int tqi = 0; tqi < 4; ++tqi) {
        l += Lpart[pair * 4 + tqi];
        bf16x8 v = *(const bf16x8*)(Opart + ((size_t)pair * 4 + tqi) * HD + d0);
#pragma unroll
        for (int j = 0; j < 8; ++j) s[j] += (float)v[j];
    }
    const float inv = 1.0f / l;
    f32x4 v0, v1;
#pragma unroll
    for (int j = 0; j < 4; ++j) { v0[j] = s[j] * inv; v1[j] = s[4 + j] * inv; }
    float* op = Out + ((size_t)(n * XLEN + x)) * D_MODEL + h * HD + d0;
    *(f32x4*)(op)     = v0;
    *(f32x4*)(op + 4) = v1;
}

extern "C" void kernel_launch(void* const* d_in, const int* in_sizes, int n_in,
                              void* d_out, int out_size, void* d_ws, size_t ws_size,
                              hipStream_t stream) {
    (void)in_sizes; (void)n_in; (void)out_size; (void)ws_size;
    const float* prev = (const float*)d_in[0];
    const float* ctx  = (const float*)d_in[1];
    const float* Wq   = (const float*)d_in[2];
    const float* bq   = (const float*)d_in[3];
    const float* Wk   = (const float*)d_in[4];
    const float* bk   = (const float*)d_in[5];
    const float* Wv   = (const float*)d_in[6];
    const float* bv   = (const float*)d_in[7];

    const size_t MiB = 1024 * 1024;
    char* ws = (char*)d_ws;
    bf16_t* prev_b = (bf16_t*)(ws);                //  4 MiB -- dead after gemm -> Lpart
    bf16_t* ctx_b  = (bf16_t*)(ws + 4 * MiB);      // 16 MiB -- dead after gemm -> Opart
    bf16_t* wq_b   = (bf16_t*)(ws + 20 * MiB);     //  2 MiB
    bf16_t* wk_b   = (bf16_t*)(ws + 22 * MiB);     //  2 MiB
    bf16_t* wv_b   = (bf16_t*)(ws + 24 * MiB);     //  2 MiB
    bf16_t* Qh     = (bf16_t*)(ws + 26 * MiB);     //  4 MiB
    bf16_t* Kh     = (bf16_t*)(ws + 30 * MiB);     // 16 MiB
    bf16_t* Vt     = (bf16_t*)(ws + 46 * MiB);     // 16 MiB (total 62 MiB)
    bf16_t* Opart  = ctx_b;                        // 16 MiB overlay
    float*  Lpart  = (float*)prev_b;               // 512 KiB overlay

    convert5<<<1664, 256, 0, stream>>>(prev, ctx, Wq, Wk, Wv, prev_b, ctx_b, wq_b, wk_b, wv_b);
    gemm_fused2<<<320, 512, 0, stream>>>(prev_b, ctx_b, wq_b, wk_b, wv_b, bq, bk, bv, Qh, Kh, Vt);
    attn_kernel<<<1024, 256, 0, stream>>>(Qh, Kh, Vt, Opart, Lpart);
    attn_merge<<<1024, 256, 0, stream>>>(Opart, Lpart, (float*)d_out);
}

// Round 13
// 194.615 us; speedup vs baseline: 1.0863x; 1.0410x over previous
//
#include <hip/hip_runtime.h>

typedef __bf16 bf16_t;
typedef __bf16 bf16x8 __attribute__((ext_vector_type(8)));
typedef __bf16 bf16x4 __attribute__((ext_vector_type(4)));
typedef float f32x4 __attribute__((ext_vector_type(4)));

#define D_MODEL 1024
#define NHEAD 16
#define HD 64
#define XLEN 1024
#define TLEN 4096
#define NBATCH 2
#define CEXP 0.18033688011112042f /* log2(e)/sqrt(64) */

typedef __attribute__((address_space(3))) bf16_t lds_bf16;
typedef const __attribute__((address_space(1))) bf16_t glb_bf16;

#define MEMFENCE() asm volatile("" ::: "memory")

// Single v_exp_f32 WITH compiler hazard handling. R12's bare inline-asm v_exp_f32
// raced the transcendental-result delay (absmax 0.091); the intrinsic lets the
// compiler insert the required wait states. Replaces __builtin_exp2f's guarded
// multi-op expansion (R11: attn VALUBusy 56% vs MfmaUtil 27% -- VALU-bound).
__device__ __forceinline__ float exp2_fast(float x) {
    return __builtin_amdgcn_exp2f(x);
}

// ---------------- convert: fp32 -> bf16, 5 arrays in one launch ----------------
__global__ __launch_bounds__(256) void convert5(const float* __restrict__ prev, const float* __restrict__ ctx,
                                                const float* __restrict__ wq, const float* __restrict__ wk,
                                                const float* __restrict__ wv,
                                                bf16_t* __restrict__ prev_b, bf16_t* __restrict__ ctx_b,
                                                bf16_t* __restrict__ wq_b, bf16_t* __restrict__ wk_b,
                                                bf16_t* __restrict__ wv_b) {
    int b = blockIdx.x;
    const float* src; bf16_t* dst; int lb;
    if (b < 256)       { src = prev; dst = prev_b; lb = b; }
    else if (b < 1280) { src = ctx;  dst = ctx_b;  lb = b - 256; }
    else if (b < 1408) { src = wq;   dst = wq_b;   lb = b - 1280; }
    else if (b < 1536) { src = wk;   dst = wk_b;   lb = b - 1408; }
    else               { src = wv;   dst = wv_b;   lb = b - 1536; }
    const int base = lb * 8192 + threadIdx.x * 4;
#pragma unroll
    for (int i = 0; i < 8; ++i) {
        const int off = base + i * 1024;
        f32x4 f = *(const f32x4*)(src + off);
        bf16x4 h;
        h[0] = (bf16_t)f[0]; h[1] = (bf16_t)f[1]; h[2] = (bf16_t)f[2]; h[3] = (bf16_t)f[3];
        *(bf16x4*)(dst + off) = h;
    }
}

// ---------------- Q-path GEMM core: BK=64, ring-2, 2-phase (R5-verified), MF=4 ----------------
template<int MF>   // MF=4: BM=128, BN=256
__device__ __forceinline__ void gemm_core(const bf16_t* __restrict__ Xa,
                                          const bf16_t* __restrict__ Wb,
                                          int m0, int n0, char* smem,
                                          f32x4 (&acc)[MF][4]) {
    const int tid  = threadIdx.x;
    const int w    = tid >> 6;
    const int lane = tid & 63;
    const int q4   = lane >> 4;
    const int c    = lane & 15;
    const int wm   = w >> 2;
    const int wn   = w & 3;

    constexpr int ABYTES = MF * 4096;
    constexpr int BUFSZ  = ABYTES + 32768;
    constexpr int AI     = MF / 4;
    constexpr int NT     = 16;

#pragma unroll
    for (int i = 0; i < MF; ++i)
#pragma unroll
        for (int j = 0; j < 4; ++j) acc[i][j] = (f32x4){0.f, 0.f, 0.f, 0.f};

    const int xp = ((lane & 3) * 16) ^ (((lane >> 5) & 1) << 5);
    const char* gA = (const char*)Xa + ((size_t)(m0 + w * 16 + (lane >> 2)) << 11) + xp;
    const char* gB = (const char*)Wb + ((size_t)(n0 + w * 16 + (lane >> 2)) << 11) + xp;
    char* lw = smem + w * 1024;
    const int fo = c * 64 + ((q4 * 16) ^ (((c >> 3) & 1) << 5));

#pragma unroll
    for (int i = 0; i < AI; ++i)
#pragma unroll
        for (int k = 0; k < 2; ++k)
            __builtin_amdgcn_global_load_lds((glb_bf16*)(gA + (size_t)i * 262144 + k * 64),
                                             (lds_bf16*)(lw + k * (MF * 2048) + i * 8192), 16, 0, 0);
#pragma unroll
    for (int i = 0; i < 2; ++i)
#pragma unroll
        for (int k = 0; k < 2; ++k)
            __builtin_amdgcn_global_load_lds((glb_bf16*)(gB + (size_t)i * 262144 + k * 64),
                                             (lds_bf16*)(lw + ABYTES + k * 16384 + i * 8192), 16, 0, 0);
    MEMFENCE();

#pragma unroll 1
    for (int t = 0; t < NT; ++t) {
        asm volatile("s_waitcnt vmcnt(0)" ::: "memory");
        __builtin_amdgcn_s_barrier();
        MEMFENCE();

        if (t + 1 < NT) {
            char* pb = lw + ((t + 1) & 1) * BUFSZ;
            const size_t tk = (size_t)(t + 1) * 128;
#pragma unroll
            for (int i = 0; i < AI; ++i)
#pragma unroll
                for (int k = 0; k < 2; ++k)
                    __builtin_amdgcn_global_load_lds((glb_bf16*)(gA + (size_t)i * 262144 + tk + k * 64),
                                                     (lds_bf16*)(pb + k * (MF * 2048) + i * 8192), 16, 0, 0);
#pragma unroll
            for (int i = 0; i < 2; ++i)
#pragma unroll
                for (int k = 0; k < 2; ++k)
                    __builtin_amdgcn_global_load_lds((glb_bf16*)(gB + (size_t)i * 262144 + tk + k * 64),
                                                     (lds_bf16*)(pb + ABYTES + k * 16384 + i * 8192), 16, 0, 0);
        }

        const char* cb = smem + (t & 1) * BUFSZ;
#pragma unroll
        for (int kk = 0; kk < 2; ++kk) {
            bf16x8 bfrag[4];
#pragma unroll
            for (int ni = 0; ni < 4; ++ni)
                bfrag[ni] = *(const bf16x8*)(cb + ABYTES + kk * 16384 + (wn * 4 + ni) * 1024 + fo);
            bf16x8 afrag[MF / 2];
#pragma unroll
            for (int mi = 0; mi < MF / 2; ++mi)
                afrag[mi] = *(const bf16x8*)(cb + kk * (MF * 2048) + (wm * MF + mi) * 1024 + fo);
            __builtin_amdgcn_s_setprio(1);
#pragma unroll
            for (int mi = 0; mi < MF / 2; ++mi)
#pragma unroll
                for (int ni = 0; ni < 4; ++ni)
                    acc[mi][ni] = __builtin_amdgcn_mfma_f32_16x16x32_bf16(afrag[mi], bfrag[ni], acc[mi][ni], 0, 0, 0);
            __builtin_amdgcn_s_setprio(0);

            bf16x8 afrag2[MF / 2];
#pragma unroll
            for (int mi = 0; mi < MF / 2; ++mi)
                afrag2[mi] = *(const bf16x8*)(cb + kk * (MF * 2048) + (wm * MF + MF / 2 + mi) * 1024 + fo);
            __builtin_amdgcn_s_setprio(1);
#pragma unroll
            for (int mi = 0; mi < MF / 2; ++mi)
#pragma unroll
                for (int ni = 0; ni < 4; ++ni)
                    acc[MF / 2 + mi][ni] = __builtin_amdgcn_mfma_f32_16x16x32_bf16(afrag2[mi], bfrag[ni], acc[MF / 2 + mi][ni], 0, 0, 0);
            __builtin_amdgcn_s_setprio(0);
            MEMFENCE();
        }
    }
}

// ---------------- KV-path GEMM core: 256x256, BK=64, 4-phase/K-tile with counted vmcnt ----------
// (R11-verified; see R10 post-mortem for the STAGE row-offset fix.)
__device__ __forceinline__ void gemm_core8(const bf16_t* __restrict__ Xa,
                                           const bf16_t* __restrict__ Wb,
                                           int m0, int n0, char* smem,
                                           f32x4 (&acc)[8][4]) {
    const int tid  = threadIdx.x;
    const int w    = tid >> 6;
    const int lane = tid & 63;
    const int q4   = lane >> 4;
    const int c    = lane & 15;
    const int wm   = w >> 2;     // 0..1 : 128-row half
    const int wn   = w & 3;      // 0..3 : 64-col group
    constexpr int NT = 16;

#pragma unroll
    for (int i = 0; i < 8; ++i)
#pragma unroll
        for (int j = 0; j < 4; ++j) acc[i][j] = (f32x4){0.f, 0.f, 0.f, 0.f};

    const int rr = lane >> 2;
    const int xp = ((lane & 3) * 16) ^ (((rr >> 3) & 1) << 5);
    const char* gA = (const char*)Xa + ((size_t)(m0 + (w >> 1) * 16 + rr) << 11) + (w & 1) * 64 + xp;
    const char* gB = (const char*)Wb + ((size_t)(n0 + (w >> 1) * 16 + rr) << 11) + (w & 1) * 64 + xp;

    const int fo = c * 64 + ((q4 * 16) ^ (((c >> 3) & 1) << 5));

    auto STAGE = [&](int tile, int j) {
        const size_t kb = (size_t)tile * 128;
        const char* g = ((j < 2) ? gA : gB) + (size_t)(j & 1) * 262144 + kb;
        char* l = smem + (tile & 1) * 65536 + ((j < 2) ? 0 : 32768) + (j & 1) * 16384 + w * 1024;
        __builtin_amdgcn_global_load_lds((glb_bf16*)(g),          (lds_bf16*)(l),        16, 0, 0);
        __builtin_amdgcn_global_load_lds((glb_bf16*)(g + 131072), (lds_bf16*)(l + 8192), 16, 0, 0);
    };

    STAGE(0, 0); STAGE(0, 1); STAGE(0, 2); STAGE(0, 3); STAGE(1, 0);
    MEMFENCE();
    asm volatile("s_waitcnt vmcnt(2)" ::: "memory");
    __builtin_amdgcn_s_barrier();
    MEMFENCE();

#pragma unroll 1
    for (int t = 0; t < NT; ++t) {
        const char* cb = smem + (t & 1) * 65536;
        const char* Ab = cb + wm * 16384;
        const char* Bb = cb + 32768 + (wn >> 1) * 16384 + (wn & 1) * 8192;

        bf16x8 a[4][2], b0[2][2], b1[2][2];

        // ---- phase 1 ----
#pragma unroll
        for (int mi = 0; mi < 4; ++mi)
#pragma unroll
            for (int kh = 0; kh < 2; ++kh)
                a[mi][kh] = *(const bf16x8*)(Ab + (mi * 2 + kh) * 1024 + fo);
#pragma unroll
        for (int ni = 0; ni < 2; ++ni)
#pragma unroll
            for (int kh = 0; kh < 2; ++kh)
                b0[ni][kh] = *(const bf16x8*)(Bb + (ni * 2 + kh) * 1024 + fo);
        if (t + 1 < NT) STAGE(t + 1, 1);
        __builtin_amdgcn_s_barrier();
        MEMFENCE();
        __builtin_amdgcn_s_setprio(1);
#pragma unroll
        for (int mi = 0; mi < 4; ++mi)
#pragma unroll
            for (int ni = 0; ni < 2; ++ni)
#pragma unroll
                for (int kh = 0; kh < 2; ++kh)
                    acc[mi][ni] = __builtin_amdgcn_mfma_f32_16x16x32_bf16(a[mi][kh], b0[ni][kh], acc[mi][ni], 0, 0, 0);
        __builtin_amdgcn_s_setprio(0);
        MEMFENCE();
        __builtin_amdgcn_s_barrier();

        // ---- phase 2 ----
#pragma unroll
        for (int ni = 0; ni < 2; ++ni)
#pragma unroll
            for (int kh = 0; kh < 2; ++kh)
                b1[ni][kh] = *(const bf16x8*)(Bb + ((2 + ni) * 2 + kh) * 1024 + fo);
        if (t + 1 < NT) STAGE(t + 1, 2);
        __builtin_amdgcn_s_barrier();
        MEMFENCE();
        __builtin_amdgcn_s_setprio(1);
#pragma unroll
        for (int mi = 0; mi < 4; ++mi)
#pragma unroll
            for (int ni = 0; ni < 2; ++ni)
#pragma unroll
                for (int kh = 0; kh < 2; ++kh)
                    acc[mi][2 + ni] = __builtin_amdgcn_mfma_f32_16x16x32_bf16(a[mi][kh], b1[ni][kh], acc[mi][2 + ni], 0, 0, 0);
        __builtin_amdgcn_s_setprio(0);
        MEMFENCE();
        __builtin_amdgcn_s_barrier();

        // ---- phase 3 ----
#pragma unroll
        for (int mi = 0; mi < 4; ++mi)
#pragma unroll
            for (int kh = 0; kh < 2; ++kh)
                a[mi][kh] = *(const bf16x8*)(Ab + ((4 + mi) * 2 + kh) * 1024 + fo);
        if (t + 1 < NT) STAGE(t + 1, 3);
        __builtin_amdgcn_s_barrier();
        MEMFENCE();
        __builtin_amdgcn_s_setprio(1);
#pragma unroll
        for (int mi = 0; mi < 4; ++mi)
#pragma unroll
            for (int ni = 0; ni < 2; ++ni)
#pragma unroll
                for (int kh = 0; kh < 2; ++kh)
                    acc[4 + mi][ni] = __builtin_amdgcn_mfma_f32_16x16x32_bf16(a[mi][kh], b0[ni][kh], acc[4 + mi][ni], 0, 0, 0);
        __builtin_amdgcn_s_setprio(0);
        MEMFENCE();
        __builtin_amdgcn_s_barrier();

        // ---- phase 4 ----
        if (t + 2 < NT) STAGE(t + 2, 0);
        __builtin_amdgcn_s_barrier();
        MEMFENCE();
        __builtin_amdgcn_s_setprio(1);
#pragma unroll
        for (int mi = 0; mi < 4; ++mi)
#pragma unroll
            for (int ni = 0; ni < 2; ++ni)
#pragma unroll
                for (int kh = 0; kh < 2; ++kh)
                    acc[4 + mi][2 + ni] = __builtin_amdgcn_mfma_f32_16x16x32_bf16(a[mi][kh], b1[ni][kh], acc[4 + mi][2 + ni], 0, 0, 0);
        __builtin_amdgcn_s_setprio(0);
        MEMFENCE();
        if (t + 1 < NT) {
            if (t + 2 < NT) asm volatile("s_waitcnt vmcnt(2)" ::: "memory");
            else            asm volatile("s_waitcnt vmcnt(0)" ::: "memory");
        }
        __builtin_amdgcn_s_barrier();
        MEMFENCE();
    }
}

// Grid (320 blocks, 512 thr):
//   bids 0..63   : Q blocks (BM=128, BN=256, 2-phase core) -- launched FIRST.
//   bids 64..319 : KV blocks (256x256, 4-phase core) = exactly 256 = one clean round.
__global__ __launch_bounds__(512, 2) void gemm_fused2(
    const bf16_t* __restrict__ Xq, const bf16_t* __restrict__ Xc,
    const bf16_t* __restrict__ wq, const bf16_t* __restrict__ wk, const bf16_t* __restrict__ wv,
    const float* __restrict__ bq, const float* __restrict__ bk, const float* __restrict__ bv,
    bf16_t* __restrict__ Qh, bf16_t* __restrict__ Kh, bf16_t* __restrict__ Vt) {
    __shared__ __align__(16) char smem[131072];
    const int bid  = blockIdx.x;
    const int tid  = threadIdx.x;
    const int w    = tid >> 6;
    const int lane = tid & 63;
    const int q4   = lane >> 4;
    const int c    = lane & 15;
    const int wm   = w >> 2;
    const int wn   = w & 3;
    (void)w;

    if (bid >= 64) {
        const int b     = bid - 64;
        const int r     = b & 7;
        const int j     = (b >> 3) & 7;
        const int mhi   = b >> 6;
        const int vmode = j >> 2;
        const int n0    = (j & 3) * 256;
        const int m0    = (mhi * 8 + r) * 256;
        const bf16_t* W   = vmode ? wv : wk;
        const float* bias = vmode ? bv : bk;

        const int Nw = n0 + wn * 64;
        float bz[4];
#pragma unroll
        for (int ni = 0; ni < 4; ++ni) bz[ni] = bias[Nw + ni * 16 + c];
        MEMFENCE();

        f32x4 acc[8][4];
        gemm_core8(Xc, W, m0, n0, smem, acc);

        const int Mw = m0 + wm * 128;
        const int headbase = Nw >> 6;
        if (vmode == 0) {
#pragma unroll
            for (int mi = 0; mi < 8; ++mi) {
                const int mrow = Mw + mi * 16 + q4 * 4;
                const int nb2 = mrow >> 12, pos = mrow & 4095;
                bf16_t* ob = Kh + ((size_t)(nb2 * NHEAD + headbase) * TLEN + pos) * HD;
#pragma unroll
                for (int ni = 0; ni < 4; ++ni) {
                    const int d = ni * 16 + c;
#pragma unroll
                    for (int r2 = 0; r2 < 4; ++r2)
                        ob[(size_t)r2 * HD + d] = (bf16_t)(acc[mi][ni][r2] + bz[ni]);
                }
            }
        } else {
#pragma unroll
            for (int mi = 0; mi < 8; ++mi) {
                const int mrow = Mw + mi * 16 + q4 * 4;
                const int nb2 = mrow >> 12, pos = mrow & 4095;
                const int lin = (pos & ~31) + ((pos >> 2) & 3) * 8 + ((pos >> 4) & 1) * 4;
#pragma unroll
                for (int ni = 0; ni < 4; ++ni) {
                    const int d = ni * 16 + c;
                    bf16x4 v4;
#pragma unroll
                    for (int r2 = 0; r2 < 4; ++r2) v4[r2] = (bf16_t)(acc[mi][ni][r2] + bz[ni]);
                    *(bf16x4*)(Vt + ((size_t)(nb2 * NHEAD + headbase) * HD + d) * TLEN + lin) = v4;
                }
            }
        }
    } else {
        const int b  = bid;
        const int m0 = (b >> 2) * 128;
        const int n0 = (b & 3) * 256;

        const int Nw = n0 + wn * 64;
        float bz[4];
#pragma unroll
        for (int ni = 0; ni < 4; ++ni) bz[ni] = bq[Nw + ni * 16 + c];
        MEMFENCE();

        f32x4 acc[4][4];
        gemm_core<4>(Xq, wq, m0, n0, smem, acc);

        const int Mw = m0 + wm * 64;
        const int headbase = Nw >> 6;
#pragma unroll
        for (int mi = 0; mi < 4; ++mi) {
            const int mrow = Mw + mi * 16 + q4 * 4;
            const int nb2 = mrow >> 10, pos = mrow & 1023;
            bf16_t* ob = Qh + ((size_t)(nb2 * NHEAD + headbase) * XLEN + pos) * HD;
#pragma unroll
            for (int ni = 0; ni < 4; ++ni) {
                const int d = ni * 16 + c;
#pragma unroll
                for (int r2 = 0; r2 < 4; ++r2)
                    ob[(size_t)r2 * HD + d] = (bf16_t)((acc[mi][ni][r2] + bz[ni]) * CEXP);
            }
        }
    }
}

// ---------------- flash attention v5.2: v5 + __builtin_amdgcn_exp2f (only change vs R11) ---------
__global__ __launch_bounds__(256, 4) void attn_kernel(const bf16_t* __restrict__ Qh,
                                                      const bf16_t* __restrict__ Kh,
                                                      const bf16_t* __restrict__ Vt,
                                                      bf16_t* __restrict__ Opart,
                                                      float* __restrict__ Lpart) {
    __shared__ __align__(16) char smem[32768];

    const int tid  = threadIdx.x;
    const int lane = tid & 63;
    const int w    = tid >> 6;
    const int q4   = lane >> 4;
    const int c    = lane & 15;

    const int bid = blockIdx.x;
    const int xcd = bid & 7;
    const int seq = bid >> 3;           // 0..127
    const int tq  = seq & 3;
    const int xb  = (seq >> 2) & 7;
    const int g   = seq >> 5;           // 0..3
    const int nh  = g * 8 + xcd;
    const int xw  = xb * 128 + w * 32;

    const bf16_t* __restrict__ Kb = Kh + (size_t)nh * TLEN * HD;
    const bf16_t* __restrict__ Vb = Vt + (size_t)nh * HD * TLEN;

    bf16x8 qa[2][2];
#pragma unroll
    for (int mi = 0; mi < 2; ++mi) {
        const bf16_t* qr = Qh + ((size_t)nh * XLEN + xw + mi * 16 + c) * HD + q4 * 8;
        qa[mi][0] = *(const bf16x8*)(qr);
        qa[mi][1] = *(const bf16x8*)(qr + 32);
    }

    const int sRow0 = tid >> 3,  sRow1 = 32 + (tid >> 3);
    const int sCh   = tid & 7;
    const int kCol0 = ((sCh ^ (sRow0 & 7)) * 8);
    const int kCol1 = ((sCh ^ (sRow1 & 7)) * 8);

    const int ofs0 = c * 128 + ((q4 ^ (c & 7)) * 16);
    const int ofs1 = c * 128 + (((4 + q4) ^ (c & 7)) * 16);

    f32x4 o[2][4];
#pragma unroll
    for (int i = 0; i < 2; ++i)
#pragma unroll
        for (int j = 0; j < 4; ++j) o[i][j] = (f32x4){0.f, 0.f, 0.f, 0.f};
    f32x4 lacc[2];
    lacc[0] = (f32x4){0.f, 0.f, 0.f, 0.f};
    lacc[1] = (f32x4){0.f, 0.f, 0.f, 0.f};

    bf16x8 ones8;
#pragma unroll
    for (int j = 0; j < 8; ++j) ones8[j] = (bf16_t)1.0f;

    const int t0base = tq * (TLEN / 4);

    {
        bf16_t* base = (bf16_t*)smem;
        __builtin_amdgcn_global_load_lds((glb_bf16*)(Kb + (size_t)(t0base + sRow0) * HD + kCol0), (lds_bf16*)(base + w * 512), 16, 0, 0);
        __builtin_amdgcn_global_load_lds((glb_bf16*)(Kb + (size_t)(t0base + sRow1) * HD + kCol1), (lds_bf16*)(base + 2048 + w * 512), 16, 0, 0);
        __builtin_amdgcn_global_load_lds((glb_bf16*)(Vb + (size_t)sRow0 * TLEN + t0base + kCol0), (lds_bf16*)(base + 4096 + w * 512), 16, 0, 0);
        __builtin_amdgcn_global_load_lds((glb_bf16*)(Vb + (size_t)sRow1 * TLEN + t0base + kCol1), (lds_bf16*)(base + 6144 + w * 512), 16, 0, 0);
    }

    for (int s = 0; s < 16; ++s) {
        __syncthreads();
        if (s < 15) {
            const int t1 = t0base + (s + 1) * 64;
            bf16_t* base = (bf16_t*)smem + ((s + 1) & 1) * 8192;
            __builtin_amdgcn_global_load_lds((glb_bf16*)(Kb + (size_t)(t1 + sRow0) * HD + kCol0), (lds_bf16*)(base + w * 512), 16, 0, 0);
            __builtin_amdgcn_global_load_lds((glb_bf16*)(Kb + (size_t)(t1 + sRow1) * HD + kCol1), (lds_bf16*)(base + 2048 + w * 512), 16, 0, 0);
            __builtin_amdgcn_global_load_lds((glb_bf16*)(Vb + (size_t)sRow0 * TLEN + t1 + kCol0), (lds_bf16*)(base + 4096 + w * 512), 16, 0, 0);
            __builtin_amdgcn_global_load_lds((glb_bf16*)(Vb + (size_t)sRow1 * TLEN + t1 + kCol1), (lds_bf16*)(base + 6144 + w * 512), 16, 0, 0);
        }

        const char* KtB = smem + (s & 1) * 16384;
        const char* VsB = KtB + 8192;
#pragma unroll
        for (int g32 = 0; g32 < 2; ++g32) {
            bf16x8 p8[2];
#pragma unroll
            for (int tt = 0; tt < 2; ++tt) {
                const int rofs = g32 * 4096 + tt * 2048;
                bf16x8 kb0 = *(const bf16x8*)(KtB + rofs + ofs0);
                bf16x8 kb1 = *(const bf16x8*)(KtB + rofs + ofs1);
#pragma unroll
                for (int mi = 0; mi < 2; ++mi) {
                    f32x4 sv = (f32x4){0.f, 0.f, 0.f, 0.f};
                    sv = __builtin_amdgcn_mfma_f32_16x16x32_bf16(kb0, qa[mi][0], sv, 0, 0, 0);
                    sv = __builtin_amdgcn_mfma_f32_16x16x32_bf16(kb1, qa[mi][1], sv, 0, 0, 0);
#pragma unroll
                    for (int r = 0; r < 4; ++r)
                        p8[mi][tt * 4 + r] = (bf16_t)exp2_fast(sv[r]);
                }
            }
            const int vsel = g32 ? ofs1 : ofs0;
            bf16x8 va[4];
#pragma unroll
            for (int dt = 0; dt < 4; ++dt)
                va[dt] = *(const bf16x8*)(VsB + vsel + dt * 2048);
#pragma unroll
            for (int mi = 0; mi < 2; ++mi) {
#pragma unroll
                for (int dt = 0; dt < 4; ++dt)
                    o[mi][dt] = __builtin_amdgcn_mfma_f32_16x16x32_bf16(va[dt], p8[mi], o[mi][dt], 0, 0, 0);
                lacc[mi] = __builtin_amdgcn_mfma_f32_16x16x32_bf16(ones8, p8[mi], lacc[mi], 0, 0, 0);
            }
        }
    }

    __syncthreads();
    bf16_t* Ob = (bf16_t*)smem;
    float*  Lb = (float*)(smem + 16896);
#pragma unroll
    for (int mi = 0; mi < 2; ++mi) {
        if (q4 == 0) Lb[w * 32 + mi * 16 + c] = lacc[mi][0];
#pragma unroll
        for (int dt = 0; dt < 4; ++dt)
#pragma unroll
            for (int r = 0; r < 4; ++r)
                Ob[w * 2112 + (dt * 16 + q4 * 4 + r) * 33 + mi * 16 + c] = (bf16_t)o[mi][dt][r];
    }
    {
        const int lr = lane >> 1;
        const int dh = lane & 1;
        bf16x8 out4[4];
#pragma unroll
        for (int j2 = 0; j2 < 4; ++j2)
#pragma unroll
            for (int e = 0; e < 8; ++e)
                out4[j2][e] = Ob[w * 2112 + (dh * 32 + j2 * 8 + e) * 33 + lr];
        const size_t pair = (size_t)nh * XLEN + xw + lr;
        bf16_t* op = Opart + (pair * 4 + tq) * HD + dh * 32;
#pragma unroll
        for (int j2 = 0; j2 < 4; ++j2)
            *(bf16x8*)(op + j2 * 8) = out4[j2];
        if (dh == 0) Lpart[pair * 4 + tq] = Lb[w * 32 + lr];
    }
}

// ---------------- merge 4 T-quarter partials, normalize, write fp32 ----------------
__global__ __launch_bounds__(256) void attn_merge(const bf16_t* __restrict__ Opart,
                                                  const float* __restrict__ Lpart,
                                                  float* __restrict__ Out) {
    const int u    = blockIdx.x * 256 + threadIdx.x;
    const int pair = u >> 3;
    const int d0   = (u & 7) * 8;
    const int nh   = pair >> 10;
    const int x    = pair & 1023;
    const int n    = nh >> 4;
    const int h    = nh & 15;

    float l = 0.f;
    float s[8];
#pragma unroll
    for (int j = 0; j < 8; ++j) s[j] = 0.f;
#pragma unroll
    for (int tqi = 0; tqi < 4; ++tqi) {
        l += Lpart[pair * 4 + tqi];
        bf16x8 v = *(const bf16x8*)(Opart + ((size_t)pair * 4 + tqi) * HD + d0);
#pragma unroll
        for (int j = 0; j < 8; ++j) s[j] += (float)v[j];
    }
    const float inv = 1.0f / l;
    f32x4 v0, v1;
#pragma unroll
    for (int j = 0; j < 4; ++j) { v0[j] = s[j] * inv; v1[j] = s[4 + j] * inv; }
    float* op = Out + ((size_t)(n * XLEN + x)) * D_MODEL + h * HD + d0;
    *(f32x4*)(op)     = v0;
    *(f32x4*)(op + 4) = v1;
}

extern "C" void kernel_launch(void* const* d_in, const int* in_sizes, int n_in,
                              void* d_out, int out_size, void* d_ws, size_t ws_size,
                              hipStream_t stream) {
    (void)in_sizes; (void)n_in; (void)out_size; (void)ws_size;
    const float* prev = (const float*)d_in[0];
    const float* ctx  = (const float*)d_in[1];
    const float* Wq   = (const float*)d_in[2];
    const float* bq   = (const float*)d_in[3];
    const float* Wk   = (const float*)d_in[4];
    const float* bk   = (const float*)d_in[5];
    const float* Wv   = (const float*)d_in[6];
    const float* bv   = (const float*)d_in[7];

    const size_t MiB = 1024 * 1024;
    char* ws = (char*)d_ws;
    bf16_t* prev_b = (bf16_t*)(ws);                //  4 MiB -- dead after gemm -> Lpart
    bf16_t* ctx_b  = (bf16_t*)(ws + 4 * MiB);      // 16 MiB -- dead after gemm -> Opart
    bf16_t* wq_b   = (bf16_t*)(ws + 20 * MiB);     //  2 MiB
    bf16_t* wk_b   = (bf16_t*)(ws + 22 * MiB);     //  2 MiB
    bf16_t* wv_b   = (bf16_t*)(ws + 24 * MiB);     //  2 MiB
    bf16_t* Qh     = (bf16_t*)(ws + 26 * MiB);     //  4 MiB
    bf16_t* Kh     = (bf16_t*)(ws + 30 * MiB);     // 16 MiB
    bf16_t* Vt     = (bf16_t*)(ws + 46 * MiB);     // 16 MiB (total 62 MiB)
    bf16_t* Opart  = ctx_b;                        // 16 MiB overlay
    float*  Lpart  = (float*)prev_b;               // 512 KiB overlay

    convert5<<<1664, 256, 0, stream>>>(prev, ctx, Wq, Wk, Wv, prev_b, ctx_b, wq_b, wk_b, wv_b);
    gemm_fused2<<<320, 512, 0, stream>>>(prev_b, ctx_b, wq_b, wk_b, wv_b, bq, bk, bv, Qh, Kh, Vt);
    attn_kernel<<<1024, 256, 0, stream>>>(Qh, Kh, Vt, Opart, Lpart);
    attn_merge<<<1024, 256, 0, stream>>>(Opart, Lpart, (float*)d_out);
}

// Round 14
// 190.663 us; speedup vs baseline: 1.1088x; 1.0207x over previous
//
#include <hip/hip_runtime.h>

typedef __bf16 bf16_t;
typedef __bf16 bf16x8 __attribute__((ext_vector_type(8)));
typedef __bf16 bf16x4 __attribute__((ext_vector_type(4)));
typedef float f32x4 __attribute__((ext_vector_type(4)));

#define D_MODEL 1024
#define NHEAD 16
#define HD 64
#define XLEN 1024
#define TLEN 4096
#define NBATCH 2
#define CEXP 0.18033688011112042f /* log2(e)/sqrt(64) */

typedef __attribute__((address_space(3))) bf16_t lds_bf16;
typedef const __attribute__((address_space(1))) bf16_t glb_bf16;

#define MEMFENCE() asm volatile("" ::: "memory")

// Single v_exp_f32 with compiler hazard handling (R13-verified: -10us on attn).
__device__ __forceinline__ float exp2_fast(float x) {
    return __builtin_amdgcn_exp2f(x);
}

// ---------------- convert: fp32 -> bf16, 5 arrays in one launch ----------------
__global__ __launch_bounds__(256) void convert5(const float* __restrict__ prev, const float* __restrict__ ctx,
                                                const float* __restrict__ wq, const float* __restrict__ wk,
                                                const float* __restrict__ wv,
                                                bf16_t* __restrict__ prev_b, bf16_t* __restrict__ ctx_b,
                                                bf16_t* __restrict__ wq_b, bf16_t* __restrict__ wk_b,
                                                bf16_t* __restrict__ wv_b) {
    int b = blockIdx.x;
    const float* src; bf16_t* dst; int lb;
    if (b < 256)       { src = prev; dst = prev_b; lb = b; }
    else if (b < 1280) { src = ctx;  dst = ctx_b;  lb = b - 256; }
    else if (b < 1408) { src = wq;   dst = wq_b;   lb = b - 1280; }
    else if (b < 1536) { src = wk;   dst = wk_b;   lb = b - 1408; }
    else               { src = wv;   dst = wv_b;   lb = b - 1536; }
    const int base = lb * 8192 + threadIdx.x * 4;
#pragma unroll
    for (int i = 0; i < 8; ++i) {
        const int off = base + i * 1024;
        f32x4 f = *(const f32x4*)(src + off);
        bf16x4 h;
        h[0] = (bf16_t)f[0]; h[1] = (bf16_t)f[1]; h[2] = (bf16_t)f[2]; h[3] = (bf16_t)f[3];
        *(bf16x4*)(dst + off) = h;
    }
}

// ---------------- GEMM core: BK=64, ring-2, 2-phase (R5-verified) ----------------
// R13's 4-phase variant REVERTED: it added ~8 barriers/K-tile (vs 1 here) and measured
// 60.5us vs this core's <=56.4 (R5/R11) -- barrier skew at 8-wave/1-block residency
// cost more than the counted-vmcnt pipeline bought.
template<int MF>   // MF = M-fragments per wave (8 -> BM=256, 4 -> BM=128); BN fixed 256
__device__ __forceinline__ void gemm_core(const bf16_t* __restrict__ Xa,
                                          const bf16_t* __restrict__ Wb,
                                          int m0, int n0, char* smem,
                                          f32x4 (&acc)[MF][4]) {
    const int tid  = threadIdx.x;
    const int w    = tid >> 6;
    const int lane = tid & 63;
    const int q4   = lane >> 4;
    const int c    = lane & 15;
    const int wm   = w >> 2;     // 0..1 : M half
    const int wn   = w & 3;      // 0..3 : 64-col group

    constexpr int ABYTES = MF * 4096;        // A bytes per buffer (32KB or 16KB)
    constexpr int BUFSZ  = ABYTES + 32768;   // + B 32KB
    constexpr int AI     = MF / 4;           // A row-groups (128 rows each)
    constexpr int NT     = 16;               // K / BK = 1024/64

#pragma unroll
    for (int i = 0; i < MF; ++i)
#pragma unroll
        for (int j = 0; j < 4; ++j) acc[i][j] = (f32x4){0.f, 0.f, 0.f, 0.f};

    const int xp = ((lane & 3) * 16) ^ (((lane >> 5) & 1) << 5);
    const char* gA = (const char*)Xa + ((size_t)(m0 + w * 16 + (lane >> 2)) << 11) + xp;
    const char* gB = (const char*)Wb + ((size_t)(n0 + w * 16 + (lane >> 2)) << 11) + xp;
    char* lw = smem + w * 1024;
    const int fo = c * 64 + ((q4 * 16) ^ (((c >> 3) & 1) << 5));

    // prologue: stage tile 0 into buffer 0
#pragma unroll
    for (int i = 0; i < AI; ++i)
#pragma unroll
        for (int k = 0; k < 2; ++k)
            __builtin_amdgcn_global_load_lds((glb_bf16*)(gA + (size_t)i * 262144 + k * 64),
                                             (lds_bf16*)(lw + k * (MF * 2048) + i * 8192), 16, 0, 0);
#pragma unroll
    for (int i = 0; i < 2; ++i)
#pragma unroll
        for (int k = 0; k < 2; ++k)
            __builtin_amdgcn_global_load_lds((glb_bf16*)(gB + (size_t)i * 262144 + k * 64),
                                             (lds_bf16*)(lw + ABYTES + k * 16384 + i * 8192), 16, 0, 0);
    MEMFENCE();

#pragma unroll 1
    for (int t = 0; t < NT; ++t) {
        asm volatile("s_waitcnt vmcnt(0)" ::: "memory");
        __builtin_amdgcn_s_barrier();
        MEMFENCE();

        if (t + 1 < NT) {
            char* pb = lw + ((t + 1) & 1) * BUFSZ;
            const size_t tk = (size_t)(t + 1) * 128;
#pragma unroll
            for (int i = 0; i < AI; ++i)
#pragma unroll
                for (int k = 0; k < 2; ++k)
                    __builtin_amdgcn_global_load_lds((glb_bf16*)(gA + (size_t)i * 262144 + tk + k * 64),
                                                     (lds_bf16*)(pb + k * (MF * 2048) + i * 8192), 16, 0, 0);
#pragma unroll
            for (int i = 0; i < 2; ++i)
#pragma unroll
                for (int k = 0; k < 2; ++k)
                    __builtin_amdgcn_global_load_lds((glb_bf16*)(gB + (size_t)i * 262144 + tk + k * 64),
                                                     (lds_bf16*)(pb + ABYTES + k * 16384 + i * 8192), 16, 0, 0);
        }

        const char* cb = smem + (t & 1) * BUFSZ;
#pragma unroll
        for (int kk = 0; kk < 2; ++kk) {
            bf16x8 bfrag[4];
#pragma unroll
            for (int ni = 0; ni < 4; ++ni)
                bfrag[ni] = *(const bf16x8*)(cb + ABYTES + kk * 16384 + (wn * 4 + ni) * 1024 + fo);
            bf16x8 afrag[MF / 2];
#pragma unroll
            for (int mi = 0; mi < MF / 2; ++mi)
                afrag[mi] = *(const bf16x8*)(cb + kk * (MF * 2048) + (wm * MF + mi) * 1024 + fo);
            __builtin_amdgcn_s_setprio(1);
#pragma unroll
            for (int mi = 0; mi < MF / 2; ++mi)
#pragma unroll
                for (int ni = 0; ni < 4; ++ni)
                    acc[mi][ni] = __builtin_amdgcn_mfma_f32_16x16x32_bf16(afrag[mi], bfrag[ni], acc[mi][ni], 0, 0, 0);
            __builtin_amdgcn_s_setprio(0);

            bf16x8 afrag2[MF / 2];
#pragma unroll
            for (int mi = 0; mi < MF / 2; ++mi)
                afrag2[mi] = *(const bf16x8*)(cb + kk * (MF * 2048) + (wm * MF + MF / 2 + mi) * 1024 + fo);
            __builtin_amdgcn_s_setprio(1);
#pragma unroll
            for (int mi = 0; mi < MF / 2; ++mi)
#pragma unroll
                for (int ni = 0; ni < 4; ++ni)
                    acc[MF / 2 + mi][ni] = __builtin_amdgcn_mfma_f32_16x16x32_bf16(afrag2[mi], bfrag[ni], acc[MF / 2 + mi][ni], 0, 0, 0);
            __builtin_amdgcn_s_setprio(0);
            MEMFENCE();
        }
    }
}

// Grid (320 blocks, 512 thr):
//   bids 0..63   : Q blocks (BM=128, BN=256) -- launched FIRST (short tail work).
//   bids 64..319 : KV blocks (BM=BN=256) = exactly 256 = one clean round.
//                  All 8 jobs {4 N-panels x K,V} of one A-panel share bid%8 -> same XCD.
__global__ __launch_bounds__(512, 2) void gemm_fused2(
    const bf16_t* __restrict__ Xq, const bf16_t* __restrict__ Xc,
    const bf16_t* __restrict__ wq, const bf16_t* __restrict__ wk, const bf16_t* __restrict__ wv,
    const float* __restrict__ bq, const float* __restrict__ bk, const float* __restrict__ bv,
    bf16_t* __restrict__ Qh, bf16_t* __restrict__ Kh, bf16_t* __restrict__ Vt) {
    __shared__ __align__(16) char smem[131072];
    const int bid  = blockIdx.x;
    const int tid  = threadIdx.x;
    const int w    = tid >> 6;
    const int lane = tid & 63;
    const int q4   = lane >> 4;
    const int c    = lane & 15;
    const int wm   = w >> 2;
    const int wn   = w & 3;
    (void)w;

    if (bid >= 64) {
        const int b     = bid - 64;
        const int r     = b & 7;          // XCD residue == m-tile low 3 bits
        const int j     = (b >> 3) & 7;   // {vmode, N-panel}
        const int mhi   = b >> 6;         // 0..3
        const int vmode = j >> 2;         // 0 = K, 1 = V
        const int n0    = (j & 3) * 256;
        const int m0    = (mhi * 8 + r) * 256;
        const bf16_t* W   = vmode ? wv : wk;
        const float* bias = vmode ? bv : bk;

        const int Nw = n0 + wn * 64;
        float bz[4];
#pragma unroll
        for (int ni = 0; ni < 4; ++ni) bz[ni] = bias[Nw + ni * 16 + c];
        MEMFENCE();

        f32x4 acc[8][4];
        gemm_core<8>(Xc, W, m0, n0, smem, acc);

        const int Mw = m0 + wm * 128;
        const int headbase = Nw >> 6;
        if (vmode == 0) {
#pragma unroll
            for (int mi = 0; mi < 8; ++mi) {
                const int mrow = Mw + mi * 16 + q4 * 4;
                const int nb2 = mrow >> 12, pos = mrow & 4095;
                bf16_t* ob = Kh + ((size_t)(nb2 * NHEAD + headbase) * TLEN + pos) * HD;
#pragma unroll
                for (int ni = 0; ni < 4; ++ni) {
                    const int d = ni * 16 + c;
#pragma unroll
                    for (int r2 = 0; r2 < 4; ++r2)
                        ob[(size_t)r2 * HD + d] = (bf16_t)(acc[mi][ni][r2] + bz[ni]);
                }
            }
        } else {
#pragma unroll
            for (int mi = 0; mi < 8; ++mi) {
                const int mrow = Mw + mi * 16 + q4 * 4;
                const int nb2 = mrow >> 12, pos = mrow & 4095;
                const int lin = (pos & ~31) + ((pos >> 2) & 3) * 8 + ((pos >> 4) & 1) * 4;
#pragma unroll
                for (int ni = 0; ni < 4; ++ni) {
                    const int d = ni * 16 + c;
                    bf16x4 v4;
#pragma unroll
                    for (int r2 = 0; r2 < 4; ++r2) v4[r2] = (bf16_t)(acc[mi][ni][r2] + bz[ni]);
                    *(bf16x4*)(Vt + ((size_t)(nb2 * NHEAD + headbase) * HD + d) * TLEN + lin) = v4;
                }
            }
        }
    } else {
        const int b  = bid;
        const int m0 = (b >> 2) * 128;
        const int n0 = (b & 3) * 256;

        const int Nw = n0 + wn * 64;
        float bz[4];
#pragma unroll
        for (int ni = 0; ni < 4; ++ni) bz[ni] = bq[Nw + ni * 16 + c];
        MEMFENCE();

        f32x4 acc[4][4];
        gemm_core<4>(Xq, wq, m0, n0, smem, acc);

        const int Mw = m0 + wm * 64;
        const int headbase = Nw >> 6;
#pragma unroll
        for (int mi = 0; mi < 4; ++mi) {
            const int mrow = Mw + mi * 16 + q4 * 4;
            const int nb2 = mrow >> 10, pos = mrow & 1023;
            bf16_t* ob = Qh + ((size_t)(nb2 * NHEAD + headbase) * XLEN + pos) * HD;
#pragma unroll
            for (int ni = 0; ni < 4; ++ni) {
                const int d = ni * 16 + c;
#pragma unroll
                for (int r2 = 0; r2 < 4; ++r2)
                    ob[(size_t)r2 * HD + d] = (bf16_t)((acc[mi][ni][r2] + bz[ni]) * CEXP);
            }
        }
    }
}

// ---------------- flash attention v5.2 (R13-verified): v5 + __builtin_amdgcn_exp2f ----------------
__global__ __launch_bounds__(256, 4) void attn_kernel(const bf16_t* __restrict__ Qh,
                                                      const bf16_t* __restrict__ Kh,
                                                      const bf16_t* __restrict__ Vt,
                                                      bf16_t* __restrict__ Opart,
                                                      float* __restrict__ Lpart) {
    __shared__ __align__(16) char smem[32768];

    const int tid  = threadIdx.x;
    const int lane = tid & 63;
    const int w    = tid >> 6;
    const int q4   = lane >> 4;
    const int c    = lane & 15;

    const int bid = blockIdx.x;
    const int xcd = bid & 7;
    const int seq = bid >> 3;           // 0..127
    const int tq  = seq & 3;
    const int xb  = (seq >> 2) & 7;
    const int g   = seq >> 5;           // 0..3
    const int nh  = g * 8 + xcd;
    const int xw  = xb * 128 + w * 32;

    const bf16_t* __restrict__ Kb = Kh + (size_t)nh * TLEN * HD;
    const bf16_t* __restrict__ Vb = Vt + (size_t)nh * HD * TLEN;

    bf16x8 qa[2][2];
#pragma unroll
    for (int mi = 0; mi < 2; ++mi) {
        const bf16_t* qr = Qh + ((size_t)nh * XLEN + xw + mi * 16 + c) * HD + q4 * 8;
        qa[mi][0] = *(const bf16x8*)(qr);
        qa[mi][1] = *(const bf16x8*)(qr + 32);
    }

    const int sRow0 = tid >> 3,  sRow1 = 32 + (tid >> 3);
    const int sCh   = tid & 7;
    const int kCol0 = ((sCh ^ (sRow0 & 7)) * 8);
    const int kCol1 = ((sCh ^ (sRow1 & 7)) * 8);

    const int ofs0 = c * 128 + ((q4 ^ (c & 7)) * 16);
    const int ofs1 = c * 128 + (((4 + q4) ^ (c & 7)) * 16);

    f32x4 o[2][4];
#pragma unroll
    for (int i = 0; i < 2; ++i)
#pragma unroll
        for (int j = 0; j < 4; ++j) o[i][j] = (f32x4){0.f, 0.f, 0.f, 0.f};
    f32x4 lacc[2];
    lacc[0] = (f32x4){0.f, 0.f, 0.f, 0.f};
    lacc[1] = (f32x4){0.f, 0.f, 0.f, 0.f};

    bf16x8 ones8;
#pragma unroll
    for (int j = 0; j < 8; ++j) ones8[j] = (bf16_t)1.0f;

    const int t0base = tq * (TLEN / 4);

    {
        bf16_t* base = (bf16_t*)smem;
        __builtin_amdgcn_global_load_lds((glb_bf16*)(Kb + (size_t)(t0base + sRow0) * HD + kCol0), (lds_bf16*)(base + w * 512), 16, 0, 0);
        __builtin_amdgcn_global_load_lds((glb_bf16*)(Kb + (size_t)(t0base + sRow1) * HD + kCol1), (lds_bf16*)(base + 2048 + w * 512), 16, 0, 0);
        __builtin_amdgcn_global_load_lds((glb_bf16*)(Vb + (size_t)sRow0 * TLEN + t0base + kCol0), (lds_bf16*)(base + 4096 + w * 512), 16, 0, 0);
        __builtin_amdgcn_global_load_lds((glb_bf16*)(Vb + (size_t)sRow1 * TLEN + t0base + kCol1), (lds_bf16*)(base + 6144 + w * 512), 16, 0, 0);
    }

    for (int s = 0; s < 16; ++s) {
        __syncthreads();
        if (s < 15) {
            const int t1 = t0base + (s + 1) * 64;
            bf16_t* base = (bf16_t*)smem + ((s + 1) & 1) * 8192;
            __builtin_amdgcn_global_load_lds((glb_bf16*)(Kb + (size_t)(t1 + sRow0) * HD + kCol0), (lds_bf16*)(base + w * 512), 16, 0, 0);
            __builtin_amdgcn_global_load_lds((glb_bf16*)(Kb + (size_t)(t1 + sRow1) * HD + kCol1), (lds_bf16*)(base + 2048 + w * 512), 16, 0, 0);
            __builtin_amdgcn_global_load_lds((glb_bf16*)(Vb + (size_t)sRow0 * TLEN + t1 + kCol0), (lds_bf16*)(base + 4096 + w * 512), 16, 0, 0);
            __builtin_amdgcn_global_load_lds((glb_bf16*)(Vb + (size_t)sRow1 * TLEN + t1 + kCol1), (lds_bf16*)(base + 6144 + w * 512), 16, 0, 0);
        }

        const char* KtB = smem + (s & 1) * 16384;
        const char* VsB = KtB + 8192;
#pragma unroll
        for (int g32 = 0; g32 < 2; ++g32) {
            bf16x8 p8[2];
#pragma unroll
            for (int tt = 0; tt < 2; ++tt) {
                const int rofs = g32 * 4096 + tt * 2048;
                bf16x8 kb0 = *(const bf16x8*)(KtB + rofs + ofs0);
                bf16x8 kb1 = *(const bf16x8*)(KtB + rofs + ofs1);
#pragma unroll
                for (int mi = 0; mi < 2; ++mi) {
                    f32x4 sv = (f32x4){0.f, 0.f, 0.f, 0.f};
                    sv = __builtin_amdgcn_mfma_f32_16x16x32_bf16(kb0, qa[mi][0], sv, 0, 0, 0);
                    sv = __builtin_amdgcn_mfma_f32_16x16x32_bf16(kb1, qa[mi][1], sv, 0, 0, 0);
#pragma unroll
                    for (int r = 0; r < 4; ++r)
                        p8[mi][tt * 4 + r] = (bf16_t)exp2_fast(sv[r]);
                }
            }
            const int vsel = g32 ? ofs1 : ofs0;
            bf16x8 va[4];
#pragma unroll
            for (int dt = 0; dt < 4; ++dt)
                va[dt] = *(const bf16x8*)(VsB + vsel + dt * 2048);
#pragma unroll
            for (int mi = 0; mi < 2; ++mi) {
#pragma unroll
                for (int dt = 0; dt < 4; ++dt)
                    o[mi][dt] = __builtin_amdgcn_mfma_f32_16x16x32_bf16(va[dt], p8[mi], o[mi][dt], 0, 0, 0);
                lacc[mi] = __builtin_amdgcn_mfma_f32_16x16x32_bf16(ones8, p8[mi], lacc[mi], 0, 0, 0);
            }
        }
    }

    __syncthreads();
    bf16_t* Ob = (bf16_t*)smem;
    float*  Lb = (float*)(smem + 16896);
#pragma unroll
    for (int mi = 0; mi < 2; ++mi) {
        if (q4 == 0) Lb[w * 32 + mi * 16 + c] = lacc[mi][0];
#pragma unroll
        for (int dt = 0; dt < 4; ++dt)
#pragma unroll
            for (int r = 0; r < 4; ++r)
                Ob[w * 2112 + (dt * 16 + q4 * 4 + r) * 33 + mi * 16 + c] = (bf16_t)o[mi][dt][r];
    }
    {
        const int lr = lane >> 1;
        const int dh = lane & 1;
        bf16x8 out4[4];
#pragma unroll
        for (int j2 = 0; j2 < 4; ++j2)
#pragma unroll
            for (int e = 0; e < 8; ++e)
                out4[j2][e] = Ob[w * 2112 + (dh * 32 + j2 * 8 + e) * 33 + lr];
        const size_t pair = (size_t)nh * XLEN + xw + lr;
        bf16_t* op = Opart + (pair * 4 + tq) * HD + dh * 32;
#pragma unroll
        for (int j2 = 0; j2 < 4; ++j2)
            *(bf16x8*)(op + j2 * 8) = out4[j2];
        if (dh == 0) Lpart[pair * 4 + tq] = Lb[w * 32 + lr];
    }
}

// ---------------- merge 4 T-quarter partials, normalize, write fp32 ----------------
__global__ __launch_bounds__(256) void attn_merge(const bf16_t* __restrict__ Opart,
                                                  const float* __restrict__ Lpart,
                                                  float* __restrict__ Out) {
    const int u    = blockIdx.x * 256 + threadIdx.x;
    const int pair = u >> 3;
    const int d0   = (u & 7) * 8;
    const int nh   = pair >> 10;
    const int x    = pair & 1023;
    const int n    = nh >> 4;
    const int h    = nh & 15;

    float l = 0.f;
    float s[8];
#pragma unroll
    for (int j = 0; j < 8; ++j) s[j] = 0.f;
#pragma unroll
    for (int tqi = 0; tqi < 4; ++tqi) {
        l += Lpart[pair * 4 + tqi];
        bf16x8 v = *(const bf16x8*)(Opart + ((size_t)pair * 4 + tqi) * HD + d0);
#pragma unroll
        for (int j = 0; j < 8; ++j) s[j] += (float)v[j];
    }
    const float inv = 1.0f / l;
    f32x4 v0, v1;
#pragma unroll
    for (int j = 0; j < 4; ++j) { v0[j] = s[j] * inv; v1[j] = s[4 + j] * inv; }
    float* op = Out + ((size_t)(n * XLEN + x)) * D_MODEL + h * HD + d0;
    *(f32x4*)(op)     = v0;
    *(f32x4*)(op + 4) = v1;
}

extern "C" void kernel_launch(void* const* d_in, const int* in_sizes, int n_in,
                              void* d_out, int out_size, void* d_ws, size_t ws_size,
                              hipStream_t stream) {
    (void)in_sizes; (void)n_in; (void)out_size; (void)ws_size;
    const float* prev = (const float*)d_in[0];
    const float* ctx  = (const float*)d_in[1];
    const float* Wq   = (const float*)d_in[2];
    const float* bq   = (const float*)d_in[3];
    const float* Wk   = (const float*)d_in[4];
    const float* bk   = (const float*)d_in[5];
    const float* Wv   = (const float*)d_in[6];
    const float* bv   = (const float*)d_in[7];

    const size_t MiB = 1024 * 1024;
    char* ws = (char*)d_ws;
    bf16_t* prev_b = (bf16_t*)(ws);                //  4 MiB -- dead after gemm -> Lpart
    bf16_t* ctx_b  = (bf16_t*)(ws + 4 * MiB);      // 16 MiB -- dead after gemm -> Opart
    bf16_t* wq_b   = (bf16_t*)(ws + 20 * MiB);     //  2 MiB
    bf16_t* wk_b   = (bf16_t*)(ws + 22 * MiB);     //  2 MiB
    bf16_t* wv_b   = (bf16_t*)(ws + 24 * MiB);     //  2 MiB
    bf16_t* Qh     = (bf16_t*)(ws + 26 * MiB);     //  4 MiB
    bf16_t* Kh     = (bf16_t*)(ws + 30 * MiB);     // 16 MiB
    bf16_t* Vt     = (bf16_t*)(ws + 46 * MiB);     // 16 MiB (total 62 MiB)
    bf16_t* Opart  = ctx_b;                        // 16 MiB overlay
    float*  Lpart  = (float*)prev_b;               // 512 KiB overlay

    convert5<<<1664, 256, 0, stream>>>(prev, ctx, Wq, Wk, Wv, prev_b, ctx_b, wq_b, wk_b, wv_b);
    gemm_fused2<<<320, 512, 0, stream>>>(prev_b, ctx_b, wq_b, wk_b, wv_b, bq, bk, bv, Qh, Kh, Vt);
    attn_kernel<<<1024, 256, 0, stream>>>(Qh, Kh, Vt, Opart, Lpart);
    attn_merge<<<1024, 256, 0, stream>>>(Opart, Lpart, (float*)d_out);
}